// Round 8
// baseline (388.745 us; speedup 1.0000x reference)
//
#include <hip/hip_runtime.h>
#include <hip/hip_bf16.h>
#include <stdint.h>

#define NODE_F 74
#define HID 128
#define DIM 256

typedef __hip_bfloat16 bf16;
typedef unsigned int u32;
typedef unsigned short u16;

typedef short s16x8 __attribute__((ext_vector_type(8)));
typedef __bf16 bf16x8 __attribute__((ext_vector_type(8)));
typedef float f32x4 __attribute__((ext_vector_type(4)));

__device__ __forceinline__ float rdl(float v, int l){
  return __int_as_float(__builtin_amdgcn_readlane(__float_as_int(v), l));
}
__device__ __forceinline__ float2 bfpair(u32 u){
  float2 r;
  r.x = __uint_as_float(u << 16);
  r.y = __uint_as_float(u & 0xffff0000u);
  return r;
}
__device__ __forceinline__ u32 packbf(float a, float b){
  u32 lo = (u32)__bfloat16_as_ushort(__float2bfloat16(a));
  u32 hi = (u32)__bfloat16_as_ushort(__float2bfloat16(b));
  return lo | (hi << 16);
}
__device__ __forceinline__ u16 bfbits(float a){
  return __bfloat16_as_ushort(__float2bfloat16(a));
}

// ---------------- degrees + weight prepack (merged) ----------------
// prep layout: dst[((t*S + s)*64 + l)*8 + e] = W[s*32 + (l>>4)*8 + e][t*16 + (l&15)]
__global__ void k_deg_prep(const int* __restrict__ src, const int* __restrict__ dst_,
                           float* __restrict__ outdeg_f, int* __restrict__ indeg, int E_,
                           const float* __restrict__ W1, const float* __restrict__ Wr1,
                           const float* __restrict__ W2, const float* __restrict__ Wr2,
                           u16* __restrict__ Bp1, u16* __restrict__ Bp2){
  int e = blockIdx.x*256 + threadIdx.x;
  if (e < E_){
    atomicAdd(&outdeg_f[src[e]], 1.0f);
    atomicAdd(&indeg[dst_[e]], 1);
  }
  int idx = e;
  if (idx < 57344){
    const float* W; u16* dstp; int S, Ktrue, loc;
    if      (idx < 12288){ W = W1;  dstp = Bp1;          S = 3; Ktrue = NODE_F; loc = idx; }
    else if (idx < 24576){ W = Wr1; dstp = Bp1 + 12288;  S = 3; Ktrue = NODE_F; loc = idx - 12288; }
    else if (idx < 40960){ W = W2;  dstp = Bp2;          S = 4; Ktrue = HID;    loc = idx - 24576; }
    else                 { W = Wr2; dstp = Bp2 + 16384;  S = 4; Ktrue = HID;    loc = idx - 40960; }
    const int el  = loc & 7;
    const int l   = (loc >> 3) & 63;
    const int rem = loc >> 9;
    const int s   = rem % S;
    const int t   = rem / S;
    const int k   = s*32 + (l >> 4)*8 + el;
    const int c   = t*16 + (l & 15);
    const float v = (k < Ktrue) ? W[(size_t)k*HID + c] : 0.f;
    dstp[loc] = bfbits(v);
  }
}

// ---------------- CSR build: 3-phase device-wide exclusive scan ----------------
__global__ __launch_bounds__(256) void k_scan_a(const int* __restrict__ indeg,
                                                float* __restrict__ norm_s,
                                                float* __restrict__ norm_d,
                                                int* __restrict__ bsum, int n){
  __shared__ int red[256];
  const int base = blockIdx.x*1024 + threadIdx.x*4;
  int s = 0;
  #pragma unroll
  for (int i = 0; i < 4; ++i){
    const int idx = base + i;
    if (idx < n){
      const int d = indeg[idx];
      s += d;
      norm_d[idx] = rsqrtf(fmaxf((float)d, 1.0f));
      norm_s[idx] = rsqrtf(fmaxf(norm_s[idx], 1.0f));
    }
  }
  red[threadIdx.x] = s;
  __syncthreads();
  #pragma unroll
  for (int off = 128; off; off >>= 1){
    if (threadIdx.x < off) red[threadIdx.x] += red[threadIdx.x + off];
    __syncthreads();
  }
  if (threadIdx.x == 0) bsum[blockIdx.x] = red[0];
}

__global__ __launch_bounds__(1024) void k_scan_b(int* __restrict__ bsum, int nb){
  __shared__ int part[1024];
  __shared__ int carry;
  if (threadIdx.x == 0) carry = 0;
  __syncthreads();
  for (int c0 = 0; c0 < nb; c0 += 1024){
    const int tid = threadIdx.x, idx = c0 + tid;
    part[tid] = (idx < nb) ? bsum[idx] : 0;
    __syncthreads();
    for (int off = 1; off < 1024; off <<= 1){
      const int t = (tid >= off) ? part[tid-off] : 0;
      __syncthreads();
      part[tid] += t;
      __syncthreads();
    }
    if (idx < nb) bsum[idx] = carry + ((tid == 0) ? 0 : part[tid-1]);
    __syncthreads();
    if (tid == 0) carry += part[1023];
    __syncthreads();
  }
}

__global__ __launch_bounds__(256) void k_scan_c(int* __restrict__ indeg,
                                                const int* __restrict__ bsum,
                                                int* __restrict__ row_ptr, int n){
  __shared__ int part[256];
  const int base = blockIdx.x*1024 + threadIdx.x*4;
  int v[4]; int s = 0;
  #pragma unroll
  for (int i = 0; i < 4; ++i){
    const int idx = base + i;
    v[i] = (idx < n) ? indeg[idx] : 0;
    s += v[i];
  }
  part[threadIdx.x] = s;
  __syncthreads();
  for (int off = 1; off < 256; off <<= 1){
    const int t = (threadIdx.x >= off) ? part[threadIdx.x-off] : 0;
    __syncthreads();
    part[threadIdx.x] += t;
    __syncthreads();
  }
  int run = bsum[blockIdx.x] + ((threadIdx.x == 0) ? 0 : part[threadIdx.x-1]);
  #pragma unroll
  for (int i = 0; i < 4; ++i){
    const int idx = base + i;
    if (idx < n){
      row_ptr[idx] = run;
      run += v[i];
      indeg[idx] = 0;
    }
    if (idx == n-1) row_ptr[n] = run;
  }
}

__global__ void k_fill(const int* __restrict__ src, const int* __restrict__ dst,
                       const int* __restrict__ row_ptr, int* __restrict__ cursor,
                       int* __restrict__ col, int E_){
  int e = blockIdx.x*256 + threadIdx.x;
  if (e < E_){
    int d = dst[e];
    int pos = row_ptr[d] + atomicAdd(&cursor[d], 1);
    col[pos] = src[e];
  }
}

// ---------------- gather1: 4 rows per wave, chunk-4 per row (16 neighbors in flight)
// agg1 = nd * sum ns*x0[nbr]  -> bf16 pairs [N][48] u32 (K padded 74->96)
__global__ __launch_bounds__(256) void k_gather1(
    const float* __restrict__ x0, const int* __restrict__ row_ptr,
    const int* __restrict__ col, const float* __restrict__ norm_s,
    const float* __restrict__ norm_d, u32* __restrict__ ag1, int n){
  const int lane = threadIdx.x & 63;
  const int wv   = (blockIdx.x*256 + threadIdx.x) >> 6;
  const int r0   = wv*4;
  if (r0 >= n) return;
  int rp[5];
  #pragma unroll
  for (int i = 0; i < 5; ++i) rp[i] = row_ptr[(r0+i < n) ? (r0+i) : n];
  int p[4], e[4];
  #pragma unroll
  for (int i = 0; i < 4; ++i){
    const bool ok = (r0+i) < n;
    p[i] = ok ? rp[i]   : 0;
    e[i] = ok ? rp[i+1] : 0;
  }
  const bool act = (lane < 37);          // 2*36+1 = 73 < 74
  const float* xb = x0 + 2*lane;
  float a0[4] = {0.f,0.f,0.f,0.f}, a1[4] = {0.f,0.f,0.f,0.f};
  while ((p[0] < e[0]) | (p[1] < e[1]) | (p[2] < e[2]) | (p[3] < e[3])){
    int c[4];
    #pragma unroll
    for (int i = 0; i < 4; ++i){
      int d = e[i] - p[i];
      c[i] = (d > 4) ? 4 : ((d < 0) ? 0 : d);
    }
    int s[4][4];
    #pragma unroll
    for (int i = 0; i < 4; ++i){
      if (c[i] > 0){
        #pragma unroll
        for (int j = 0; j < 4; ++j)
          s[i][j] = col[p[i] + ((j < c[i]) ? j : (c[i]-1))];
      }
    }
    float nw[4][4];
    float2 v[4][4];
    #pragma unroll
    for (int i = 0; i < 4; ++i){
      #pragma unroll
      for (int j = 0; j < 4; ++j){ nw[i][j] = 0.f; v[i][j] = float2{0.f,0.f}; }
      if (c[i] > 0){
        #pragma unroll
        for (int j = 0; j < 4; ++j) nw[i][j] = (j < c[i]) ? norm_s[s[i][j]] : 0.f;
        if (act){
          #pragma unroll
          for (int j = 0; j < 4; ++j) v[i][j] = *(const float2*)&xb[(size_t)s[i][j]*NODE_F];
        }
      }
    }
    #pragma unroll
    for (int i = 0; i < 4; ++i){
      a0[i] = fmaf(v[i][0].x, nw[i][0], fmaf(v[i][1].x, nw[i][1],
              fmaf(v[i][2].x, nw[i][2], fmaf(v[i][3].x, nw[i][3], a0[i]))));
      a1[i] = fmaf(v[i][0].y, nw[i][0], fmaf(v[i][1].y, nw[i][1],
              fmaf(v[i][2].y, nw[i][2], fmaf(v[i][3].y, nw[i][3], a1[i]))));
      p[i] += c[i];
    }
  }
  if (lane < 48){                        // pads k 74..95 with zeros
    #pragma unroll
    for (int i = 0; i < 4; ++i){
      const int row = r0 + i;
      if (row < n){
        const float nd = norm_d[row];
        ag1[(size_t)row*48 + lane] = packbf(a0[i]*nd, a1[i]*nd);
      }
    }
  }
}

// ---------------- gather2: 4 rows per wave from bf16 h1 [N][128] ----------------
__global__ __launch_bounds__(256) void k_gather2(
    const u32* __restrict__ h1u, const int* __restrict__ row_ptr,
    const int* __restrict__ col, const float* __restrict__ norm_s,
    const float* __restrict__ norm_d, u32* __restrict__ ag2, int n){
  const int lane = threadIdx.x & 63;
  const int wv   = (blockIdx.x*256 + threadIdx.x) >> 6;
  const int r0   = wv*4;
  if (r0 >= n) return;
  int rp[5];
  #pragma unroll
  for (int i = 0; i < 5; ++i) rp[i] = row_ptr[(r0+i < n) ? (r0+i) : n];
  int p[4], e[4];
  #pragma unroll
  for (int i = 0; i < 4; ++i){
    const bool ok = (r0+i) < n;
    p[i] = ok ? rp[i]   : 0;
    e[i] = ok ? rp[i+1] : 0;
  }
  const u32* hb = h1u + lane;
  float a0[4] = {0.f,0.f,0.f,0.f}, a1[4] = {0.f,0.f,0.f,0.f};
  while ((p[0] < e[0]) | (p[1] < e[1]) | (p[2] < e[2]) | (p[3] < e[3])){
    int c[4];
    #pragma unroll
    for (int i = 0; i < 4; ++i){
      int d = e[i] - p[i];
      c[i] = (d > 4) ? 4 : ((d < 0) ? 0 : d);
    }
    int s[4][4];
    #pragma unroll
    for (int i = 0; i < 4; ++i){
      if (c[i] > 0){
        #pragma unroll
        for (int j = 0; j < 4; ++j)
          s[i][j] = col[p[i] + ((j < c[i]) ? j : (c[i]-1))];
      }
    }
    float nw[4][4];
    u32 v[4][4];
    #pragma unroll
    for (int i = 0; i < 4; ++i){
      #pragma unroll
      for (int j = 0; j < 4; ++j){ nw[i][j] = 0.f; v[i][j] = 0u; }
      if (c[i] > 0){
        #pragma unroll
        for (int j = 0; j < 4; ++j) nw[i][j] = (j < c[i]) ? norm_s[s[i][j]] : 0.f;
        #pragma unroll
        for (int j = 0; j < 4; ++j) v[i][j] = hb[(size_t)s[i][j]*64];
      }
    }
    #pragma unroll
    for (int i = 0; i < 4; ++i){
      const float2 f0 = bfpair(v[i][0]), f1 = bfpair(v[i][1]);
      const float2 f2 = bfpair(v[i][2]), f3 = bfpair(v[i][3]);
      a0[i] = fmaf(f0.x, nw[i][0], fmaf(f1.x, nw[i][1],
              fmaf(f2.x, nw[i][2], fmaf(f3.x, nw[i][3], a0[i]))));
      a1[i] = fmaf(f0.y, nw[i][0], fmaf(f1.y, nw[i][1],
              fmaf(f2.y, nw[i][2], fmaf(f3.y, nw[i][3], a1[i]))));
      p[i] += c[i];
    }
  }
  #pragma unroll
  for (int i = 0; i < 4; ++i){
    const int row = r0 + i;
    if (row < n){
      const float nd = norm_d[row];
      ag2[(size_t)row*64 + lane] = packbf(a0[i]*nd, a1[i]*nd);
    }
  }
}

// ---------------- dense GEMM layer1: A = ag1 (bf16 [N][96]) / residual x0 -> h1
__global__ __launch_bounds__(256) void k_ggemm1(
    const u16* __restrict__ ag1, const float* __restrict__ x0,
    const u16* __restrict__ Bp, const float* __restrict__ bg_,
    const float* __restrict__ br_, u16* __restrict__ h1, int n){
  const int lane = threadIdx.x & 63;
  const int wid  = threadIdx.x >> 6;
  const int jg = lane & 15, kg = lane >> 4;
  const int r0 = blockIdx.x*64 + wid*16;
  const int row = r0 + jg;
  const bool rok = row < n;
  const int kb = kg*8;
  const int rA = rok ? row : (n-1);

  bf16x8 ag[3], ar[3];
  #pragma unroll
  for (int s = 0; s < 3; ++s)
    ag[s] = __builtin_bit_cast(bf16x8, *(const s16x8*)&ag1[(size_t)rA*96 + s*32 + kb]);
  {
    const float* px = x0 + (size_t)rA*NODE_F;
    #pragma unroll
    for (int s = 0; s < 2; ++s)
      #pragma unroll
      for (int e = 0; e < 8; e += 2){
        const float2 w = *(const float2*)&px[s*32 + kb + e];
        ar[s][e]   = (__bf16)w.x;
        ar[s][e+1] = (__bf16)w.y;
      }
    #pragma unroll
    for (int e = 0; e < 8; ++e) ar[2][e] = (__bf16)0.f;
    if (kg == 0){
      #pragma unroll
      for (int e = 0; e < 8; e += 2){
        const float2 w = *(const float2*)&px[64 + e];
        ar[2][e]   = (__bf16)w.x;
        ar[2][e+1] = (__bf16)w.y;
      }
    } else if (kg == 1){
      const float2 w = *(const float2*)&px[72];
      ar[2][0] = (__bf16)w.x;
      ar[2][1] = (__bf16)w.y;
    }
  }

  f32x4 accg[8], accr[8];
  #pragma unroll
  for (int t = 0; t < 8; ++t){
    accg[t] = f32x4{0.f,0.f,0.f,0.f};
    accr[t] = f32x4{0.f,0.f,0.f,0.f};
  }
  constexpr int FR1 = 8*3*512;
  #pragma unroll
  for (int s = 0; s < 3; ++s){
    #pragma unroll
    for (int t = 0; t < 8; ++t){
      const bf16x8 bg = __builtin_bit_cast(bf16x8,
          *(const s16x8*)&Bp[((t*3 + s)*64 + lane)*8]);
      const bf16x8 br = __builtin_bit_cast(bf16x8,
          *(const s16x8*)&Bp[FR1 + ((t*3 + s)*64 + lane)*8]);
      accg[t] = __builtin_amdgcn_mfma_f32_16x16x32_bf16(ag[s], bg, accg[t], 0,0,0);
      accr[t] = __builtin_amdgcn_mfma_f32_16x16x32_bf16(ar[s], br, accr[t], 0,0,0);
    }
  }

  const int rowb = r0 + 4*kg;
  #pragma unroll
  for (int t = 0; t < 8; ++t){
    const int colc = t*16 + jg;
    const float bgv = bg_[colc], brv = br_[colc];
    #pragma unroll
    for (int r = 0; r < 4; ++r){
      const int row2 = rowb + r;
      if (row2 < n){
        const float o = fmaxf(accg[t][r] + bgv, 0.f) + fmaxf(accr[t][r] + brv, 0.f);
        h1[(size_t)row2*HID + colc] = bfbits(o);
      }
    }
  }
}

// ---------------- dense GEMM layer2 + fused readout ----------------
__global__ __launch_bounds__(256) void k_ggemm2(
    const u16* __restrict__ ag2, const u16* __restrict__ h1,
    const u16* __restrict__ Bp, const float* __restrict__ bg_,
    const float* __restrict__ br_,
    const float* __restrict__ w_atom, const float* __restrict__ b_atom,
    const int* __restrict__ gid,
    float* __restrict__ hsum, u32* __restrict__ hmax, int n){
  const int lane = threadIdx.x & 63;
  const int wid  = threadIdx.x >> 6;
  const int jg = lane & 15, kg = lane >> 4;
  const int r0 = blockIdx.x*64 + wid*16;
  const int row = r0 + jg;
  const bool rok = row < n;
  const int kb = kg*8;
  const int rA = rok ? row : (n-1);

  f32x4 accg[8], accr[8];
  #pragma unroll
  for (int t = 0; t < 8; ++t){
    accg[t] = f32x4{0.f,0.f,0.f,0.f};
    accr[t] = f32x4{0.f,0.f,0.f,0.f};
  }
  constexpr int FR2 = 8*4*512;
  #pragma unroll
  for (int s = 0; s < 4; ++s){
    const bf16x8 agf = __builtin_bit_cast(bf16x8,
        *(const s16x8*)&ag2[(size_t)rA*HID + s*32 + kb]);
    const bf16x8 arf = __builtin_bit_cast(bf16x8,
        *(const s16x8*)&h1[(size_t)rA*HID + s*32 + kb]);
    #pragma unroll
    for (int t = 0; t < 8; ++t){
      const bf16x8 bg = __builtin_bit_cast(bf16x8,
          *(const s16x8*)&Bp[((t*4 + s)*64 + lane)*8]);
      const bf16x8 br = __builtin_bit_cast(bf16x8,
          *(const s16x8*)&Bp[FR2 + ((t*4 + s)*64 + lane)*8]);
      accg[t] = __builtin_amdgcn_mfma_f32_16x16x32_bf16(agf, bg, accg[t], 0,0,0);
      accr[t] = __builtin_amdgcn_mfma_f32_16x16x32_bf16(arf, br, accr[t], 0,0,0);
    }
  }

  float o[8][4];
  #pragma unroll
  for (int t = 0; t < 8; ++t){
    const int colc = t*16 + jg;
    const float bgv = bg_[colc], brv = br_[colc];
    #pragma unroll
    for (int r = 0; r < 4; ++r)
      o[t][r] = fmaxf(accg[t][r] + bgv, 0.f) + fmaxf(accr[t][r] + brv, 0.f);
  }
  if (r0 < n){
    float wa[8];
    #pragma unroll
    for (int t = 0; t < 8; ++t) wa[t] = w_atom[t*16 + jg];
    const float ba = b_atom[0];
    const int rowb = r0 + 4*kg;
    float awv[4]; int gidr[4];
    #pragma unroll
    for (int r = 0; r < 4; ++r){
      const int row2 = rowb + r;
      float dot = 0.f;
      #pragma unroll
      for (int t = 0; t < 8; ++t) dot = fmaf(o[t][r], wa[t], dot);
      dot += __shfl_xor(dot, 1);
      dot += __shfl_xor(dot, 2);
      dot += __shfl_xor(dot, 4);
      dot += __shfl_xor(dot, 8);
      awv[r]  = 1.0f/(1.0f + __expf(-(dot + ba)));
      gidr[r] = (row2 < n) ? gid[row2] : -1;
    }
    const int rhi    = (r0 + 15 < n) ? (r0 + 15) : (n - 1);
    const int gfirst = gid[r0];
    const int glast  = gid[rhi];
    for (int g = gfirst; g <= glast; ++g){
      #pragma unroll
      for (int t = 0; t < 8; ++t){
        float sv = 0.f, mv = 0.f;
        #pragma unroll
        for (int r = 0; r < 4; ++r){
          const bool in = (gidr[r] == g);
          sv += in ? o[t][r]*awv[r] : 0.f;
          mv  = in ? fmaxf(mv, o[t][r]) : mv;
        }
        sv += __shfl_xor(sv, 16);
        sv += __shfl_xor(sv, 32);
        mv  = fmaxf(mv, __shfl_xor(mv, 16));
        mv  = fmaxf(mv, __shfl_xor(mv, 32));
        if (lane < 16){
          atomicAdd(&hsum[(size_t)g*HID + t*16 + jg], sv);
          atomicMax(&hmax[(size_t)g*HID + t*16 + jg], __float_as_uint(mv));  // o >= 0
        }
      }
    }
  }
}

// ---------------- fused MLP: latent = relu(gfeat@Wp1+bp1)@Wp2+bp2, zero-row insert
__global__ __launch_bounds__(256) void k_mlp(
    const float* __restrict__ hsum, const float* __restrict__ hmaxf,
    const float* __restrict__ Wp1, const float* __restrict__ bp1,
    const float* __restrict__ Wp2, const float* __restrict__ bp2,
    const int* __restrict__ idxw, int K_,
    float* __restrict__ out, int G_){
  const int lane = threadIdx.x & 63;
  const int row = blockIdx.x*4 + (threadIdx.x >> 6);
  if (blockIdx.x == 0){
    for (int j = 0; j < K_; ++j){
      const int zr = idxw[j];
      for (int i = threadIdx.x; i < DIM; i += 256)
        out[(size_t)zr*DIM + i] = 0.f;
    }
  }
  if (row >= G_) return;
  const int c = lane*2;
  float ra0 = hsum [(size_t)row*HID + lane];
  float ra1 = hsum [(size_t)row*HID + 64 + lane];
  float ra2 = hmaxf[(size_t)row*HID + lane];
  float ra3 = hmaxf[(size_t)row*HID + 64 + lane];
  float a0 = 0.f, a1 = 0.f;
  #pragma unroll 4
  for (int k = 0; k < 64; ++k){
    const float v0 = rdl(ra0,k), v1 = rdl(ra1,k), v2 = rdl(ra2,k), v3 = rdl(ra3,k);
    const float2 w0 = *(const float2*)&Wp1[(size_t)(k      )*HID + c];
    const float2 w1 = *(const float2*)&Wp1[(size_t)(k +  64)*HID + c];
    const float2 w2 = *(const float2*)&Wp1[(size_t)(k + 128)*HID + c];
    const float2 w3 = *(const float2*)&Wp1[(size_t)(k + 192)*HID + c];
    a0 = fmaf(v0,w0.x, fmaf(v1,w1.x, fmaf(v2,w2.x, fmaf(v3,w3.x, a0))));
    a1 = fmaf(v0,w0.y, fmaf(v1,w1.y, fmaf(v2,w2.y, fmaf(v3,w3.y, a1))));
  }
  const float h0  = fmaxf(a0 + bp1[c],   0.f);
  const float h1v = fmaxf(a1 + bp1[c+1], 0.f);
  const int c4 = lane*4;
  float acc0=0.f, acc1=0.f, acc2=0.f, acc3=0.f;
  #pragma unroll 4
  for (int j = 0; j < 64; ++j){
    const float he = rdl(h0, j);
    const float ho = rdl(h1v, j);
    const float4 we = *(const float4*)&Wp2[(size_t)(2*j  )*DIM + c4];
    const float4 wo = *(const float4*)&Wp2[(size_t)(2*j+1)*DIM + c4];
    acc0 = fmaf(he,we.x, fmaf(ho,wo.x, acc0));
    acc1 = fmaf(he,we.y, fmaf(ho,wo.y, acc1));
    acc2 = fmaf(he,we.z, fmaf(ho,wo.z, acc2));
    acc3 = fmaf(he,we.w, fmaf(ho,wo.w, acc3));
  }
  int orow = row;
  for (int j = 0; j < K_; ++j){ if (idxw[j] <= orow) orow++; }
  float* po = out + (size_t)orow*DIM + c4;
  po[0] = acc0 + bp2[c4];
  po[1] = acc1 + bp2[c4+1];
  po[2] = acc2 + bp2[c4+2];
  po[3] = acc3 + bp2[c4+3];
}

extern "C" void kernel_launch(void* const* d_in, const int* in_sizes, int n_in,
                              void* d_out, int out_size, void* d_ws, size_t ws_size,
                              hipStream_t stream){
  (void)n_in; (void)ws_size;
  const float* x0     = (const float*)d_in[0];
  const float* W1     = (const float*)d_in[2];
  const float* b1     = (const float*)d_in[3];
  const float* Wr1    = (const float*)d_in[4];
  const float* br1    = (const float*)d_in[5];
  const float* W2     = (const float*)d_in[6];
  const float* b2     = (const float*)d_in[7];
  const float* Wr2    = (const float*)d_in[8];
  const float* br2    = (const float*)d_in[9];
  const float* w_atom = (const float*)d_in[10];
  const float* b_atom = (const float*)d_in[11];
  const float* Wp1    = (const float*)d_in[12];
  const float* bp1    = (const float*)d_in[13];
  const float* Wp2    = (const float*)d_in[14];
  const float* bp2    = (const float*)d_in[15];
  const int* src  = (const int*)d_in[16];
  const int* dst  = (const int*)d_in[17];
  const int* gid  = (const int*)d_in[18];
  const int* idxw = (const int*)d_in[19];

  const int N_ = in_sizes[0] / NODE_F;
  const int E_ = in_sizes[16];
  const int K_ = in_sizes[19];
  const int G_ = out_size / DIM - K_;

  // workspace (~59 MB, proven in rounds 6-7):
  //  [h1 bf16 N*128][norm_d N]
  //  zero-region: [norm_s N][hsum G*128][hmax G*128][indeg N]
  //  [row_ptr N+1 pad][col E pad][bsum nscan][agg u32 N*64]
  u16*   h1     = (u16*)d_ws;
  float* norm_d = (float*)(h1 + (size_t)N_*HID);
  float* norm_s = norm_d + N_;
  float* hsum   = norm_s + N_;
  float* hmaxv  = hsum + (size_t)G_*HID;
  int*   indeg  = (int*)(hmaxv + (size_t)G_*HID);
  int*   row_ptr= indeg + N_;
  int*   col    = row_ptr + ((N_ + 4) & ~3);
  int*   bsum   = col + ((E_ + 4) & ~3);
  const int nscan = (N_ + 1023)/1024;
  uintptr_t aggp = ((uintptr_t)(bsum + nscan) + 255) & ~(uintptr_t)255;
  u32* aggu = (u32*)aggp;                              // [N][64] u32 (25.6 MB)

  // weight-fragment scratch in d_out (112 KB; fully overwritten by k_mlp later)
  u16*   Bp1    = (u16*)d_out;                         // 2*12288 u16
  u16*   Bp2    = Bp1 + 2*12288;                       // 2*16384 u16

  hipMemsetAsync(norm_s, 0, ((size_t)2*N_ + (size_t)2*G_*HID)*sizeof(float), stream);

  k_deg_prep<<<(E_+255)/256, 256, 0, stream>>>(src, dst, norm_s, indeg, E_,
                                               W1, Wr1, W2, Wr2, Bp1, Bp2);
  k_scan_a  <<<nscan, 256, 0, stream>>>(indeg, norm_s, norm_d, bsum, N_);
  k_scan_b  <<<1, 1024, 0, stream>>>(bsum, nscan);
  k_scan_c  <<<nscan, 256, 0, stream>>>(indeg, bsum, row_ptr, N_);
  k_fill    <<<(E_+255)/256, 256, 0, stream>>>(src, dst, row_ptr, indeg, col, E_);

  const int nb  = (N_ + 63) / 64;
  const int nbw = (N_ + 15) / 16;   // 4 waves/block x 4 rows/wave
  k_gather1<<<nbw, 256, 0, stream>>>(x0, row_ptr, col, norm_s, norm_d, aggu, N_);
  k_ggemm1 <<<nb, 256, 0, stream>>>((const u16*)aggu, x0, Bp1, b1, br1, h1, N_);
  k_gather2<<<nbw, 256, 0, stream>>>((const u32*)h1, row_ptr, col, norm_s, norm_d,
                                     aggu, N_);
  k_ggemm2 <<<nb, 256, 0, stream>>>((const u16*)aggu, h1, Bp2, b2, br2,
                                    w_atom, b_atom, gid, hsum, (u32*)hmaxv, N_);

  k_mlp<<<(G_+3)/4, 256, 0, stream>>>(hsum, hmaxv, Wp1, bp1, Wp2, bp2,
                                      idxw, K_, (float*)d_out, G_);
}

// Round 9
// 367.546 us; speedup vs baseline: 1.0577x; 1.0577x over previous
//
#include <hip/hip_runtime.h>
#include <hip/hip_bf16.h>
#include <stdint.h>

#define NODE_F 74
#define HID 128
#define DIM 256

typedef __hip_bfloat16 bf16;
typedef unsigned int u32;
typedef unsigned short u16;

typedef short s16x8 __attribute__((ext_vector_type(8)));
typedef __bf16 bf16x8 __attribute__((ext_vector_type(8)));
typedef float f32x4 __attribute__((ext_vector_type(4)));

__device__ __forceinline__ float rdl(float v, int l){
  return __int_as_float(__builtin_amdgcn_readlane(__float_as_int(v), l));
}
__device__ __forceinline__ float2 bfpair(u32 u){
  float2 r;
  r.x = __uint_as_float(u << 16);
  r.y = __uint_as_float(u & 0xffff0000u);
  return r;
}
__device__ __forceinline__ u32 packbf(float a, float b){
  u32 lo = (u32)__bfloat16_as_ushort(__float2bfloat16(a));
  u32 hi = (u32)__bfloat16_as_ushort(__float2bfloat16(b));
  return lo | (hi << 16);
}
__device__ __forceinline__ u16 bfbits(float a){
  return __bfloat16_as_ushort(__float2bfloat16(a));
}

// ---------------- degrees + weight prepack (merged) ----------------
// prep layout: dst[((t*S + s)*64 + l)*8 + e] = W[s*32 + (l>>4)*8 + e][t*16 + (l&15)]
__global__ void k_deg_prep(const int* __restrict__ src, const int* __restrict__ dst_,
                           float* __restrict__ outdeg_f, int* __restrict__ indeg, int E_,
                           const float* __restrict__ W1, const float* __restrict__ Wr1,
                           const float* __restrict__ W2, const float* __restrict__ Wr2,
                           u16* __restrict__ Bp1, u16* __restrict__ Bp2){
  int e = blockIdx.x*256 + threadIdx.x;
  if (e < E_){
    atomicAdd(&outdeg_f[src[e]], 1.0f);
    atomicAdd(&indeg[dst_[e]], 1);
  }
  int idx = e;
  if (idx < 57344){
    const float* W; u16* dstp; int S, Ktrue, loc;
    if      (idx < 12288){ W = W1;  dstp = Bp1;          S = 3; Ktrue = NODE_F; loc = idx; }
    else if (idx < 24576){ W = Wr1; dstp = Bp1 + 12288;  S = 3; Ktrue = NODE_F; loc = idx - 12288; }
    else if (idx < 40960){ W = W2;  dstp = Bp2;          S = 4; Ktrue = HID;    loc = idx - 24576; }
    else                 { W = Wr2; dstp = Bp2 + 16384;  S = 4; Ktrue = HID;    loc = idx - 40960; }
    const int el  = loc & 7;
    const int l   = (loc >> 3) & 63;
    const int rem = loc >> 9;
    const int s   = rem % S;
    const int t   = rem / S;
    const int k   = s*32 + (l >> 4)*8 + el;
    const int c   = t*16 + (l & 15);
    const float v = (k < Ktrue) ? W[(size_t)k*HID + c] : 0.f;
    dstp[loc] = bfbits(v);
  }
}

// ---------------- CSR build: 3-phase device-wide exclusive scan ----------------
__global__ __launch_bounds__(256) void k_scan_a(const int* __restrict__ indeg,
                                                float* __restrict__ norm_s,
                                                float* __restrict__ norm_d,
                                                int* __restrict__ bsum, int n){
  __shared__ int red[256];
  const int base = blockIdx.x*1024 + threadIdx.x*4;
  int s = 0;
  #pragma unroll
  for (int i = 0; i < 4; ++i){
    const int idx = base + i;
    if (idx < n){
      const int d = indeg[idx];
      s += d;
      norm_d[idx] = rsqrtf(fmaxf((float)d, 1.0f));
      norm_s[idx] = rsqrtf(fmaxf(norm_s[idx], 1.0f));
    }
  }
  red[threadIdx.x] = s;
  __syncthreads();
  #pragma unroll
  for (int off = 128; off; off >>= 1){
    if (threadIdx.x < off) red[threadIdx.x] += red[threadIdx.x + off];
    __syncthreads();
  }
  if (threadIdx.x == 0) bsum[blockIdx.x] = red[0];
}

__global__ __launch_bounds__(1024) void k_scan_b(int* __restrict__ bsum, int nb){
  __shared__ int part[1024];
  __shared__ int carry;
  if (threadIdx.x == 0) carry = 0;
  __syncthreads();
  for (int c0 = 0; c0 < nb; c0 += 1024){
    const int tid = threadIdx.x, idx = c0 + tid;
    part[tid] = (idx < nb) ? bsum[idx] : 0;
    __syncthreads();
    for (int off = 1; off < 1024; off <<= 1){
      const int t = (tid >= off) ? part[tid-off] : 0;
      __syncthreads();
      part[tid] += t;
      __syncthreads();
    }
    if (idx < nb) bsum[idx] = carry + ((tid == 0) ? 0 : part[tid-1]);
    __syncthreads();
    if (tid == 0) carry += part[1023];
    __syncthreads();
  }
}

__global__ __launch_bounds__(256) void k_scan_c(int* __restrict__ indeg,
                                                const int* __restrict__ bsum,
                                                int* __restrict__ row_ptr, int n){
  __shared__ int part[256];
  const int base = blockIdx.x*1024 + threadIdx.x*4;
  int v[4]; int s = 0;
  #pragma unroll
  for (int i = 0; i < 4; ++i){
    const int idx = base + i;
    v[i] = (idx < n) ? indeg[idx] : 0;
    s += v[i];
  }
  part[threadIdx.x] = s;
  __syncthreads();
  for (int off = 1; off < 256; off <<= 1){
    const int t = (threadIdx.x >= off) ? part[threadIdx.x-off] : 0;
    __syncthreads();
    part[threadIdx.x] += t;
    __syncthreads();
  }
  int run = bsum[blockIdx.x] + ((threadIdx.x == 0) ? 0 : part[threadIdx.x-1]);
  #pragma unroll
  for (int i = 0; i < 4; ++i){
    const int idx = base + i;
    if (idx < n){
      row_ptr[idx] = run;
      run += v[i];
      indeg[idx] = 0;
    }
    if (idx == n-1) row_ptr[n] = run;
  }
}

// ---------------- CSR fill + (optional) pre-scaled bf16 x0 conversion ----------
// x0bf[r*48 + l] = packbf(ns*x0[r][2l], ns*x0[r][2l+1])  (features >=74 -> 0)
__global__ void k_fill_conv(const int* __restrict__ src, const int* __restrict__ dst,
                            const int* __restrict__ row_ptr, int* __restrict__ cursor,
                            int* __restrict__ col, int E_,
                            const float* __restrict__ x0,
                            const float* __restrict__ norm_s,
                            u32* __restrict__ x0bf, int n, int do_conv){
  int e = blockIdx.x*256 + threadIdx.x;
  if (e < E_){
    int d = dst[e];
    int pos = row_ptr[d] + atomicAdd(&cursor[d], 1);
    col[pos] = src[e];
  }
  if (do_conv){
    const int tot = n*48;
    if (e < tot){
      const int r = e/48, l = e - r*48;
      const int f0 = 2*l, f1 = 2*l + 1;
      const float ns = norm_s[r];
      const float u0 = (f0 < NODE_F) ? ns*x0[(size_t)r*NODE_F + f0] : 0.f;
      const float u1 = (f1 < NODE_F) ? ns*x0[(size_t)r*NODE_F + f1] : 0.f;
      x0bf[e] = packbf(u0, u1);
    }
  }
}

// ---------------- gather1b: 2 rows/wave from pre-scaled bf16 x0 [N][48] ------
__global__ __launch_bounds__(256, 8) void k_gather1b(
    const u32* __restrict__ x0bf, const int* __restrict__ row_ptr,
    const int* __restrict__ col, const float* __restrict__ norm_d,
    u32* __restrict__ ag1, int n){
  const int lane = threadIdx.x & 63;
  const int wv   = (blockIdx.x*256 + threadIdx.x) >> 6;
  const int r0   = wv*2;
  if (r0 >= n) return;
  int p[2], e[2];
  p[0] = row_ptr[r0]; e[0] = row_ptr[r0+1];
  const bool ok1 = (r0+1) < n;
  p[1] = ok1 ? e[0] : 0;
  e[1] = ok1 ? row_ptr[r0+2] : 0;
  const bool act = (lane < 48);
  const u32* xb = x0bf + lane;
  float a0[2] = {0.f,0.f}, a1[2] = {0.f,0.f};
  while ((p[0] < e[0]) | (p[1] < e[1])){
    int c[2], s[2][4];
    #pragma unroll
    for (int i = 0; i < 2; ++i){
      int d = e[i] - p[i];
      c[i] = (d > 4) ? 4 : ((d < 0) ? 0 : d);
      if (c[i] > 0){
        #pragma unroll
        for (int j = 0; j < 4; ++j)
          s[i][j] = col[p[i] + ((j < c[i]) ? j : (c[i]-1))];
      }
    }
    u32 v[2][4];
    #pragma unroll
    for (int i = 0; i < 2; ++i){
      #pragma unroll
      for (int j = 0; j < 4; ++j) v[i][j] = 0u;
      if (c[i] > 0 && act){
        #pragma unroll
        for (int j = 0; j < 4; ++j){
          const u32 t = xb[(size_t)s[i][j]*48];
          v[i][j] = (j < c[i]) ? t : 0u;    // cndmask: dup-index pads contribute 0
        }
      }
    }
    #pragma unroll
    for (int i = 0; i < 2; ++i){
      const float2 f0 = bfpair(v[i][0]), f1 = bfpair(v[i][1]);
      const float2 f2 = bfpair(v[i][2]), f3 = bfpair(v[i][3]);
      a0[i] += (f0.x + f1.x) + (f2.x + f3.x);
      a1[i] += (f0.y + f1.y) + (f2.y + f3.y);
      p[i] += c[i];
    }
  }
  if (lane < 48){
    #pragma unroll
    for (int i = 0; i < 2; ++i){
      const int row = r0 + i;
      if (row < n){
        const float nd = norm_d[row];
        ag1[(size_t)row*48 + lane] = packbf(a0[i]*nd, a1[i]*nd);
      }
    }
  }
}

// ---------------- gather2b: 2 rows/wave from bf16 h1 [N][128] ----------------
__global__ __launch_bounds__(256, 8) void k_gather2b(
    const u32* __restrict__ h1u, const int* __restrict__ row_ptr,
    const int* __restrict__ col, const float* __restrict__ norm_s,
    const float* __restrict__ norm_d, u32* __restrict__ ag2, int n){
  const int lane = threadIdx.x & 63;
  const int wv   = (blockIdx.x*256 + threadIdx.x) >> 6;
  const int r0   = wv*2;
  if (r0 >= n) return;
  int p[2], e[2];
  p[0] = row_ptr[r0]; e[0] = row_ptr[r0+1];
  const bool ok1 = (r0+1) < n;
  p[1] = ok1 ? e[0] : 0;
  e[1] = ok1 ? row_ptr[r0+2] : 0;
  const u32* hb = h1u + lane;
  float a0[2] = {0.f,0.f}, a1[2] = {0.f,0.f};
  while ((p[0] < e[0]) | (p[1] < e[1])){
    int c[2], s[2][4];
    #pragma unroll
    for (int i = 0; i < 2; ++i){
      int d = e[i] - p[i];
      c[i] = (d > 4) ? 4 : ((d < 0) ? 0 : d);
      if (c[i] > 0){
        #pragma unroll
        for (int j = 0; j < 4; ++j)
          s[i][j] = col[p[i] + ((j < c[i]) ? j : (c[i]-1))];
      }
    }
    float nw[2][4];
    u32 v[2][4];
    #pragma unroll
    for (int i = 0; i < 2; ++i){
      #pragma unroll
      for (int j = 0; j < 4; ++j){ nw[i][j] = 0.f; v[i][j] = 0u; }
      if (c[i] > 0){
        #pragma unroll
        for (int j = 0; j < 4; ++j) nw[i][j] = (j < c[i]) ? norm_s[s[i][j]] : 0.f;
        #pragma unroll
        for (int j = 0; j < 4; ++j) v[i][j] = hb[(size_t)s[i][j]*64];
      }
    }
    #pragma unroll
    for (int i = 0; i < 2; ++i){
      const float2 f0 = bfpair(v[i][0]), f1 = bfpair(v[i][1]);
      const float2 f2 = bfpair(v[i][2]), f3 = bfpair(v[i][3]);
      a0[i] = fmaf(f0.x, nw[i][0], fmaf(f1.x, nw[i][1],
              fmaf(f2.x, nw[i][2], fmaf(f3.x, nw[i][3], a0[i]))));
      a1[i] = fmaf(f0.y, nw[i][0], fmaf(f1.y, nw[i][1],
              fmaf(f2.y, nw[i][2], fmaf(f3.y, nw[i][3], a1[i]))));
      p[i] += c[i];
    }
  }
  #pragma unroll
  for (int i = 0; i < 2; ++i){
    const int row = r0 + i;
    if (row < n){
      const float nd = norm_d[row];
      ag2[(size_t)row*64 + lane] = packbf(a0[i]*nd, a1[i]*nd);
    }
  }
}

// ---------------- fallback gathers (round-7 proven, f32 x0) ------------------
__global__ __launch_bounds__(256) void k_gather1f(
    const float* __restrict__ x0, const int* __restrict__ row_ptr,
    const int* __restrict__ col, const float* __restrict__ norm_s,
    const float* __restrict__ norm_d, u32* __restrict__ ag1, int n){
  const int lane = threadIdx.x & 63;
  const int row  = blockIdx.x*4 + (threadIdx.x >> 6);
  if (row >= n) return;
  const int p0 = row_ptr[row], p1 = row_ptr[row+1];
  const bool act = (lane < 37);
  const float* xb = x0 + 2*lane;
  float a0 = 0.f, a1 = 0.f;
  int p = p0;
  #pragma unroll 1
  for (; p + 3 < p1; p += 4){
    const int s0 = col[p], s1 = col[p+1], s2 = col[p+2], s3 = col[p+3];
    const float n0 = norm_s[s0], n1 = norm_s[s1], n2 = norm_s[s2], n3 = norm_s[s3];
    float2 v0{0.f,0.f}, v1{0.f,0.f}, v2{0.f,0.f}, v3{0.f,0.f};
    if (act){
      v0 = *(const float2*)&xb[(size_t)s0*NODE_F];
      v1 = *(const float2*)&xb[(size_t)s1*NODE_F];
      v2 = *(const float2*)&xb[(size_t)s2*NODE_F];
      v3 = *(const float2*)&xb[(size_t)s3*NODE_F];
    }
    a0 = fmaf(v0.x,n0, fmaf(v1.x,n1, fmaf(v2.x,n2, fmaf(v3.x,n3, a0))));
    a1 = fmaf(v0.y,n0, fmaf(v1.y,n1, fmaf(v2.y,n2, fmaf(v3.y,n3, a1))));
  }
  const int rem = p1 - p;
  if (rem > 0){
    const int s0 = col[p];
    int s1 = s0, s2 = s0;
    float n1 = 0.f, n2 = 0.f;
    const float n0 = norm_s[s0];
    if (rem > 1){ s1 = col[p+1]; n1 = norm_s[s1]; }
    if (rem > 2){ s2 = col[p+2]; n2 = norm_s[s2]; }
    float2 v0{0.f,0.f}, v1{0.f,0.f}, v2{0.f,0.f};
    if (act){
      v0 = *(const float2*)&xb[(size_t)s0*NODE_F];
      v1 = *(const float2*)&xb[(size_t)s1*NODE_F];
      v2 = *(const float2*)&xb[(size_t)s2*NODE_F];
    }
    a0 = fmaf(v0.x,n0, fmaf(v1.x,n1, fmaf(v2.x,n2, a0)));
    a1 = fmaf(v0.y,n0, fmaf(v1.y,n1, fmaf(v2.y,n2, a1)));
  }
  if (lane < 48){
    const float nd = norm_d[row];
    ag1[(size_t)row*48 + lane] = packbf(a0*nd, a1*nd);
  }
}

__global__ __launch_bounds__(256) void k_gather2f(
    const u32* __restrict__ h1u, const int* __restrict__ row_ptr,
    const int* __restrict__ col, const float* __restrict__ norm_s,
    const float* __restrict__ norm_d, u32* __restrict__ ag2, int n){
  const int lane = threadIdx.x & 63;
  const int row  = blockIdx.x*4 + (threadIdx.x >> 6);
  if (row >= n) return;
  const int p0 = row_ptr[row], p1 = row_ptr[row+1];
  const u32* hb = h1u + lane;
  float a0 = 0.f, a1 = 0.f;
  int p = p0;
  #pragma unroll 1
  for (; p + 3 < p1; p += 4){
    const int s0 = col[p], s1 = col[p+1], s2 = col[p+2], s3 = col[p+3];
    const float n0 = norm_s[s0], n1 = norm_s[s1], n2 = norm_s[s2], n3 = norm_s[s3];
    const u32 u0 = hb[(size_t)s0*64];
    const u32 u1 = hb[(size_t)s1*64];
    const u32 u2 = hb[(size_t)s2*64];
    const u32 u3 = hb[(size_t)s3*64];
    const float2 f0 = bfpair(u0), f1 = bfpair(u1), f2 = bfpair(u2), f3 = bfpair(u3);
    a0 = fmaf(f0.x,n0, fmaf(f1.x,n1, fmaf(f2.x,n2, fmaf(f3.x,n3, a0))));
    a1 = fmaf(f0.y,n0, fmaf(f1.y,n1, fmaf(f2.y,n2, fmaf(f3.y,n3, a1))));
  }
  const int rem = p1 - p;
  if (rem > 0){
    const int s0 = col[p];
    int s1 = s0, s2 = s0;
    float n1 = 0.f, n2 = 0.f;
    const float n0 = norm_s[s0];
    if (rem > 1){ s1 = col[p+1]; n1 = norm_s[s1]; }
    if (rem > 2){ s2 = col[p+2]; n2 = norm_s[s2]; }
    const u32 u0 = hb[(size_t)s0*64];
    const u32 u1 = hb[(size_t)s1*64];
    const u32 u2 = hb[(size_t)s2*64];
    const float2 f0 = bfpair(u0), f1 = bfpair(u1), f2 = bfpair(u2);
    a0 = fmaf(f0.x,n0, fmaf(f1.x,n1, fmaf(f2.x,n2, a0)));
    a1 = fmaf(f0.y,n0, fmaf(f1.y,n1, fmaf(f2.y,n2, a1)));
  }
  const float nd = norm_d[row];
  ag2[(size_t)row*64 + lane] = packbf(a0*nd, a1*nd);
}

// ---------------- dense GEMM layer1: A = ag1 (bf16 [N][96]) / residual x0 -> h1
__global__ __launch_bounds__(256) void k_ggemm1(
    const u16* __restrict__ ag1, const float* __restrict__ x0,
    const u16* __restrict__ Bp, const float* __restrict__ bg_,
    const float* __restrict__ br_, u16* __restrict__ h1, int n){
  const int lane = threadIdx.x & 63;
  const int wid  = threadIdx.x >> 6;
  const int jg = lane & 15, kg = lane >> 4;
  const int r0 = blockIdx.x*64 + wid*16;
  const int row = r0 + jg;
  const bool rok = row < n;
  const int kb = kg*8;
  const int rA = rok ? row : (n-1);

  bf16x8 ag[3], ar[3];
  #pragma unroll
  for (int s = 0; s < 3; ++s)
    ag[s] = __builtin_bit_cast(bf16x8, *(const s16x8*)&ag1[(size_t)rA*96 + s*32 + kb]);
  {
    const float* px = x0 + (size_t)rA*NODE_F;
    #pragma unroll
    for (int s = 0; s < 2; ++s)
      #pragma unroll
      for (int e = 0; e < 8; e += 2){
        const float2 w = *(const float2*)&px[s*32 + kb + e];
        ar[s][e]   = (__bf16)w.x;
        ar[s][e+1] = (__bf16)w.y;
      }
    #pragma unroll
    for (int e = 0; e < 8; ++e) ar[2][e] = (__bf16)0.f;
    if (kg == 0){
      #pragma unroll
      for (int e = 0; e < 8; e += 2){
        const float2 w = *(const float2*)&px[64 + e];
        ar[2][e]   = (__bf16)w.x;
        ar[2][e+1] = (__bf16)w.y;
      }
    } else if (kg == 1){
      const float2 w = *(const float2*)&px[72];
      ar[2][0] = (__bf16)w.x;
      ar[2][1] = (__bf16)w.y;
    }
  }

  f32x4 accg[8], accr[8];
  #pragma unroll
  for (int t = 0; t < 8; ++t){
    accg[t] = f32x4{0.f,0.f,0.f,0.f};
    accr[t] = f32x4{0.f,0.f,0.f,0.f};
  }
  constexpr int FR1 = 8*3*512;
  #pragma unroll
  for (int s = 0; s < 3; ++s){
    #pragma unroll
    for (int t = 0; t < 8; ++t){
      const bf16x8 bg = __builtin_bit_cast(bf16x8,
          *(const s16x8*)&Bp[((t*3 + s)*64 + lane)*8]);
      const bf16x8 br = __builtin_bit_cast(bf16x8,
          *(const s16x8*)&Bp[FR1 + ((t*3 + s)*64 + lane)*8]);
      accg[t] = __builtin_amdgcn_mfma_f32_16x16x32_bf16(ag[s], bg, accg[t], 0,0,0);
      accr[t] = __builtin_amdgcn_mfma_f32_16x16x32_bf16(ar[s], br, accr[t], 0,0,0);
    }
  }

  const int rowb = r0 + 4*kg;
  #pragma unroll
  for (int t = 0; t < 8; ++t){
    const int colc = t*16 + jg;
    const float bgv = bg_[colc], brv = br_[colc];
    #pragma unroll
    for (int r = 0; r < 4; ++r){
      const int row2 = rowb + r;
      if (row2 < n){
        const float o = fmaxf(accg[t][r] + bgv, 0.f) + fmaxf(accr[t][r] + brv, 0.f);
        h1[(size_t)row2*HID + colc] = bfbits(o);
      }
    }
  }
}

// ---------------- dense GEMM layer2 + fused readout ----------------
__global__ __launch_bounds__(256) void k_ggemm2(
    const u16* __restrict__ ag2, const u16* __restrict__ h1,
    const u16* __restrict__ Bp, const float* __restrict__ bg_,
    const float* __restrict__ br_,
    const float* __restrict__ w_atom, const float* __restrict__ b_atom,
    const int* __restrict__ gid,
    float* __restrict__ hsum, u32* __restrict__ hmax, int n){
  const int lane = threadIdx.x & 63;
  const int wid  = threadIdx.x >> 6;
  const int jg = lane & 15, kg = lane >> 4;
  const int r0 = blockIdx.x*64 + wid*16;
  const int row = r0 + jg;
  const bool rok = row < n;
  const int kb = kg*8;
  const int rA = rok ? row : (n-1);

  f32x4 accg[8], accr[8];
  #pragma unroll
  for (int t = 0; t < 8; ++t){
    accg[t] = f32x4{0.f,0.f,0.f,0.f};
    accr[t] = f32x4{0.f,0.f,0.f,0.f};
  }
  constexpr int FR2 = 8*4*512;
  #pragma unroll
  for (int s = 0; s < 4; ++s){
    const bf16x8 agf = __builtin_bit_cast(bf16x8,
        *(const s16x8*)&ag2[(size_t)rA*HID + s*32 + kb]);
    const bf16x8 arf = __builtin_bit_cast(bf16x8,
        *(const s16x8*)&h1[(size_t)rA*HID + s*32 + kb]);
    #pragma unroll
    for (int t = 0; t < 8; ++t){
      const bf16x8 bg = __builtin_bit_cast(bf16x8,
          *(const s16x8*)&Bp[((t*4 + s)*64 + lane)*8]);
      const bf16x8 br = __builtin_bit_cast(bf16x8,
          *(const s16x8*)&Bp[FR2 + ((t*4 + s)*64 + lane)*8]);
      accg[t] = __builtin_amdgcn_mfma_f32_16x16x32_bf16(agf, bg, accg[t], 0,0,0);
      accr[t] = __builtin_amdgcn_mfma_f32_16x16x32_bf16(arf, br, accr[t], 0,0,0);
    }
  }

  float o[8][4];
  #pragma unroll
  for (int t = 0; t < 8; ++t){
    const int colc = t*16 + jg;
    const float bgv = bg_[colc], brv = br_[colc];
    #pragma unroll
    for (int r = 0; r < 4; ++r)
      o[t][r] = fmaxf(accg[t][r] + bgv, 0.f) + fmaxf(accr[t][r] + brv, 0.f);
  }
  if (r0 < n){
    float wa[8];
    #pragma unroll
    for (int t = 0; t < 8; ++t) wa[t] = w_atom[t*16 + jg];
    const float ba = b_atom[0];
    const int rowb = r0 + 4*kg;
    float awv[4]; int gidr[4];
    #pragma unroll
    for (int r = 0; r < 4; ++r){
      const int row2 = rowb + r;
      float dot = 0.f;
      #pragma unroll
      for (int t = 0; t < 8; ++t) dot = fmaf(o[t][r], wa[t], dot);
      dot += __shfl_xor(dot, 1);
      dot += __shfl_xor(dot, 2);
      dot += __shfl_xor(dot, 4);
      dot += __shfl_xor(dot, 8);
      awv[r]  = 1.0f/(1.0f + __expf(-(dot + ba)));
      gidr[r] = (row2 < n) ? gid[row2] : -1;
    }
    const int rhi    = (r0 + 15 < n) ? (r0 + 15) : (n - 1);
    const int gfirst = gid[r0];
    const int glast  = gid[rhi];
    for (int g = gfirst; g <= glast; ++g){
      #pragma unroll
      for (int t = 0; t < 8; ++t){
        float sv = 0.f, mv = 0.f;
        #pragma unroll
        for (int r = 0; r < 4; ++r){
          const bool in = (gidr[r] == g);
          sv += in ? o[t][r]*awv[r] : 0.f;
          mv  = in ? fmaxf(mv, o[t][r]) : mv;
        }
        sv += __shfl_xor(sv, 16);
        sv += __shfl_xor(sv, 32);
        mv  = fmaxf(mv, __shfl_xor(mv, 16));
        mv  = fmaxf(mv, __shfl_xor(mv, 32));
        if (lane < 16){
          atomicAdd(&hsum[(size_t)g*HID + t*16 + jg], sv);
          atomicMax(&hmax[(size_t)g*HID + t*16 + jg], __float_as_uint(mv));  // o >= 0
        }
      }
    }
  }
}

// ---------------- fused MLP: latent = relu(gfeat@Wp1+bp1)@Wp2+bp2, zero-row insert
__global__ __launch_bounds__(256) void k_mlp(
    const float* __restrict__ hsum, const float* __restrict__ hmaxf,
    const float* __restrict__ Wp1, const float* __restrict__ bp1,
    const float* __restrict__ Wp2, const float* __restrict__ bp2,
    const int* __restrict__ idxw, int K_,
    float* __restrict__ out, int G_){
  const int lane = threadIdx.x & 63;
  const int row = blockIdx.x*4 + (threadIdx.x >> 6);
  if (blockIdx.x == 0){
    for (int j = 0; j < K_; ++j){
      const int zr = idxw[j];
      for (int i = threadIdx.x; i < DIM; i += 256)
        out[(size_t)zr*DIM + i] = 0.f;
    }
  }
  if (row >= G_) return;
  const int c = lane*2;
  float ra0 = hsum [(size_t)row*HID + lane];
  float ra1 = hsum [(size_t)row*HID + 64 + lane];
  float ra2 = hmaxf[(size_t)row*HID + lane];
  float ra3 = hmaxf[(size_t)row*HID + 64 + lane];
  float a0 = 0.f, a1 = 0.f;
  #pragma unroll 4
  for (int k = 0; k < 64; ++k){
    const float v0 = rdl(ra0,k), v1 = rdl(ra1,k), v2 = rdl(ra2,k), v3 = rdl(ra3,k);
    const float2 w0 = *(const float2*)&Wp1[(size_t)(k      )*HID + c];
    const float2 w1 = *(const float2*)&Wp1[(size_t)(k +  64)*HID + c];
    const float2 w2 = *(const float2*)&Wp1[(size_t)(k + 128)*HID + c];
    const float2 w3 = *(const float2*)&Wp1[(size_t)(k + 192)*HID + c];
    a0 = fmaf(v0,w0.x, fmaf(v1,w1.x, fmaf(v2,w2.x, fmaf(v3,w3.x, a0))));
    a1 = fmaf(v0,w0.y, fmaf(v1,w1.y, fmaf(v2,w2.y, fmaf(v3,w3.y, a1))));
  }
  const float h0  = fmaxf(a0 + bp1[c],   0.f);
  const float h1v = fmaxf(a1 + bp1[c+1], 0.f);
  const int c4 = lane*4;
  float acc0=0.f, acc1=0.f, acc2=0.f, acc3=0.f;
  #pragma unroll 4
  for (int j = 0; j < 64; ++j){
    const float he = rdl(h0, j);
    const float ho = rdl(h1v, j);
    const float4 we = *(const float4*)&Wp2[(size_t)(2*j  )*DIM + c4];
    const float4 wo = *(const float4*)&Wp2[(size_t)(2*j+1)*DIM + c4];
    acc0 = fmaf(he,we.x, fmaf(ho,wo.x, acc0));
    acc1 = fmaf(he,we.y, fmaf(ho,wo.y, acc1));
    acc2 = fmaf(he,we.z, fmaf(ho,wo.z, acc2));
    acc3 = fmaf(he,we.w, fmaf(ho,wo.w, acc3));
  }
  int orow = row;
  for (int j = 0; j < K_; ++j){ if (idxw[j] <= orow) orow++; }
  float* po = out + (size_t)orow*DIM + c4;
  po[0] = acc0 + bp2[c4];
  po[1] = acc1 + bp2[c4+1];
  po[2] = acc2 + bp2[c4+2];
  po[3] = acc3 + bp2[c4+3];
}

extern "C" void kernel_launch(void* const* d_in, const int* in_sizes, int n_in,
                              void* d_out, int out_size, void* d_ws, size_t ws_size,
                              hipStream_t stream){
  (void)n_in;
  const float* x0     = (const float*)d_in[0];
  const float* W1     = (const float*)d_in[2];
  const float* b1     = (const float*)d_in[3];
  const float* Wr1    = (const float*)d_in[4];
  const float* br1    = (const float*)d_in[5];
  const float* W2     = (const float*)d_in[6];
  const float* b2     = (const float*)d_in[7];
  const float* Wr2    = (const float*)d_in[8];
  const float* br2    = (const float*)d_in[9];
  const float* w_atom = (const float*)d_in[10];
  const float* b_atom = (const float*)d_in[11];
  const float* Wp1    = (const float*)d_in[12];
  const float* bp1    = (const float*)d_in[13];
  const float* Wp2    = (const float*)d_in[14];
  const float* bp2    = (const float*)d_in[15];
  const int* src  = (const int*)d_in[16];
  const int* dst  = (const int*)d_in[17];
  const int* gid  = (const int*)d_in[18];
  const int* idxw = (const int*)d_in[19];

  const int N_ = in_sizes[0] / NODE_F;
  const int E_ = in_sizes[16];
  const int K_ = in_sizes[19];
  const int G_ = out_size / DIM - K_;

  // workspace:
  //  [h1 bf16 N*128][norm_d N]
  //  zero-region: [norm_s N][hsum G*128][hmax G*128][indeg N]
  //  [row_ptr N+1 pad][col E pad][bsum nscan][agg u32 N*64][x0bf u32 N*48 optional]
  u16*   h1     = (u16*)d_ws;
  float* norm_d = (float*)(h1 + (size_t)N_*HID);
  float* norm_s = norm_d + N_;
  float* hsum   = norm_s + N_;
  float* hmaxv  = hsum + (size_t)G_*HID;
  int*   indeg  = (int*)(hmaxv + (size_t)G_*HID);
  int*   row_ptr= indeg + N_;
  int*   col    = row_ptr + ((N_ + 4) & ~3);
  int*   bsum   = col + ((E_ + 4) & ~3);
  const int nscan = (N_ + 1023)/1024;
  uintptr_t aggp = ((uintptr_t)(bsum + nscan) + 255) & ~(uintptr_t)255;
  u32* aggu = (u32*)aggp;                              // [N][64] u32 (25.6 MB)
  uintptr_t x0bfp = aggp + (size_t)N_*64*sizeof(u32);  // stays 256-aligned
  u32* x0bf = (u32*)x0bfp;                             // [N][48] u32 (19.2 MB)
  const size_t need_bf = (x0bfp + (size_t)N_*48*sizeof(u32)) - (uintptr_t)d_ws;
  const bool use_bf = (ws_size >= need_bf);

  // weight-fragment scratch in d_out (112 KB; fully overwritten by k_mlp later)
  u16*   Bp1    = (u16*)d_out;                         // 2*12288 u16
  u16*   Bp2    = Bp1 + 2*12288;                       // 2*16384 u16

  hipMemsetAsync(norm_s, 0, ((size_t)2*N_ + (size_t)2*G_*HID)*sizeof(float), stream);

  k_deg_prep<<<(E_+255)/256, 256, 0, stream>>>(src, dst, norm_s, indeg, E_,
                                               W1, Wr1, W2, Wr2, Bp1, Bp2);
  k_scan_a  <<<nscan, 256, 0, stream>>>(indeg, norm_s, norm_d, bsum, N_);
  k_scan_b  <<<1, 1024, 0, stream>>>(bsum, nscan);
  k_scan_c  <<<nscan, 256, 0, stream>>>(indeg, bsum, row_ptr, N_);

  const int conv_tot = use_bf ? (N_*48 > E_ ? N_*48 : E_) : E_;
  k_fill_conv<<<(conv_tot+255)/256, 256, 0, stream>>>(
      src, dst, row_ptr, indeg, col, E_, x0, norm_s,
      use_bf ? x0bf : aggu, N_, use_bf ? 1 : 0);

  const int nb   = (N_ + 63) / 64;
  const int nbw  = (N_ + 3) / 4;     // fallback: 1 row/wave
  const int nbw2 = (N_ + 7) / 8;     // 2 rows/wave, 4 waves/block
  if (use_bf){
    k_gather1b<<<nbw2, 256, 0, stream>>>(x0bf, row_ptr, col, norm_d, aggu, N_);
  } else {
    k_gather1f<<<nbw, 256, 0, stream>>>(x0, row_ptr, col, norm_s, norm_d, aggu, N_);
  }
  k_ggemm1<<<nb, 256, 0, stream>>>((const u16*)aggu, x0, Bp1, b1, br1, h1, N_);
  if (use_bf){
    k_gather2b<<<nbw2, 256, 0, stream>>>((const u32*)h1, row_ptr, col, norm_s,
                                         norm_d, aggu, N_);
  } else {
    k_gather2f<<<nbw, 256, 0, stream>>>((const u32*)h1, row_ptr, col, norm_s,
                                        norm_d, aggu, N_);
  }
  k_ggemm2<<<nb, 256, 0, stream>>>((const u16*)aggu, h1, Bp2, b2, br2,
                                   w_atom, b_atom, gid, hsum, (u32*)hmaxv, N_);

  k_mlp<<<(G_+3)/4, 256, 0, stream>>>(hsum, hmaxv, Wp1, bp1, Wp2, bp2,
                                      idxw, K_, (float*)d_out, G_);
}

// Round 10
// 337.758 us; speedup vs baseline: 1.1510x; 1.0882x over previous
//
#include <hip/hip_runtime.h>
#include <hip/hip_bf16.h>
#include <stdint.h>

#define NODE_F 74
#define HID 128
#define DIM 256

typedef __hip_bfloat16 bf16;
typedef unsigned int u32;
typedef unsigned short u16;

typedef short s16x8 __attribute__((ext_vector_type(8)));
typedef __bf16 bf16x8 __attribute__((ext_vector_type(8)));
typedef float f32x4 __attribute__((ext_vector_type(4)));

__device__ __forceinline__ float rdl(float v, int l){
  return __int_as_float(__builtin_amdgcn_readlane(__float_as_int(v), l));
}
__device__ __forceinline__ float2 bfpair(u32 u){
  float2 r;
  r.x = __uint_as_float(u << 16);
  r.y = __uint_as_float(u & 0xffff0000u);
  return r;
}
__device__ __forceinline__ u32 packbf(float a, float b){
  u32 lo = (u32)__bfloat16_as_ushort(__float2bfloat16(a));
  u32 hi = (u32)__bfloat16_as_ushort(__float2bfloat16(b));
  return lo | (hi << 16);
}
__device__ __forceinline__ u16 bfbits(float a){
  return __bfloat16_as_ushort(__float2bfloat16(a));
}

// ---------------- degrees + weight prepack (merged) ----------------
__global__ void k_deg_prep(const int* __restrict__ src, const int* __restrict__ dst_,
                           float* __restrict__ outdeg_f, int* __restrict__ indeg, int E_,
                           const float* __restrict__ W1, const float* __restrict__ Wr1,
                           const float* __restrict__ W2, const float* __restrict__ Wr2,
                           u16* __restrict__ Bp1, u16* __restrict__ Bp2){
  int e = blockIdx.x*256 + threadIdx.x;
  if (e < E_){
    atomicAdd(&outdeg_f[src[e]], 1.0f);
    atomicAdd(&indeg[dst_[e]], 1);
  }
  int idx = e;
  if (idx < 57344){
    const float* W; u16* dstp; int S, Ktrue, loc;
    if      (idx < 12288){ W = W1;  dstp = Bp1;          S = 3; Ktrue = NODE_F; loc = idx; }
    else if (idx < 24576){ W = Wr1; dstp = Bp1 + 12288;  S = 3; Ktrue = NODE_F; loc = idx - 12288; }
    else if (idx < 40960){ W = W2;  dstp = Bp2;          S = 4; Ktrue = HID;    loc = idx - 24576; }
    else                 { W = Wr2; dstp = Bp2 + 16384;  S = 4; Ktrue = HID;    loc = idx - 40960; }
    const int el  = loc & 7;
    const int l   = (loc >> 3) & 63;
    const int rem = loc >> 9;
    const int s   = rem % S;
    const int t   = rem / S;
    const int k   = s*32 + (l >> 4)*8 + el;
    const int c   = t*16 + (l & 15);
    const float v = (k < Ktrue) ? W[(size_t)k*HID + c] : 0.f;
    dstp[loc] = bfbits(v);
  }
}

// ---------------- CSR build: 3-phase device-wide exclusive scan ----------------
__global__ __launch_bounds__(256) void k_scan_a(const int* __restrict__ indeg,
                                                float* __restrict__ norm_s,
                                                float* __restrict__ norm_d,
                                                int* __restrict__ bsum, int n){
  __shared__ int red[256];
  const int base = blockIdx.x*1024 + threadIdx.x*4;
  int s = 0;
  #pragma unroll
  for (int i = 0; i < 4; ++i){
    const int idx = base + i;
    if (idx < n){
      const int d = indeg[idx];
      s += d;
      norm_d[idx] = rsqrtf(fmaxf((float)d, 1.0f));
      norm_s[idx] = rsqrtf(fmaxf(norm_s[idx], 1.0f));
    }
  }
  red[threadIdx.x] = s;
  __syncthreads();
  #pragma unroll
  for (int off = 128; off; off >>= 1){
    if (threadIdx.x < off) red[threadIdx.x] += red[threadIdx.x + off];
    __syncthreads();
  }
  if (threadIdx.x == 0) bsum[blockIdx.x] = red[0];
}

__global__ __launch_bounds__(1024) void k_scan_b(int* __restrict__ bsum, int nb){
  __shared__ int part[1024];
  __shared__ int carry;
  if (threadIdx.x == 0) carry = 0;
  __syncthreads();
  for (int c0 = 0; c0 < nb; c0 += 1024){
    const int tid = threadIdx.x, idx = c0 + tid;
    part[tid] = (idx < nb) ? bsum[idx] : 0;
    __syncthreads();
    for (int off = 1; off < 1024; off <<= 1){
      const int t = (tid >= off) ? part[tid-off] : 0;
      __syncthreads();
      part[tid] += t;
      __syncthreads();
    }
    if (idx < nb) bsum[idx] = carry + ((tid == 0) ? 0 : part[tid-1]);
    __syncthreads();
    if (tid == 0) carry += part[1023];
    __syncthreads();
  }
}

__global__ __launch_bounds__(256) void k_scan_c(int* __restrict__ indeg,
                                                const int* __restrict__ bsum,
                                                int* __restrict__ row_ptr, int n){
  __shared__ int part[256];
  const int base = blockIdx.x*1024 + threadIdx.x*4;
  int v[4]; int s = 0;
  #pragma unroll
  for (int i = 0; i < 4; ++i){
    const int idx = base + i;
    v[i] = (idx < n) ? indeg[idx] : 0;
    s += v[i];
  }
  part[threadIdx.x] = s;
  __syncthreads();
  for (int off = 1; off < 256; off <<= 1){
    const int t = (threadIdx.x >= off) ? part[threadIdx.x-off] : 0;
    __syncthreads();
    part[threadIdx.x] += t;
    __syncthreads();
  }
  int run = bsum[blockIdx.x] + ((threadIdx.x == 0) ? 0 : part[threadIdx.x-1]);
  #pragma unroll
  for (int i = 0; i < 4; ++i){
    const int idx = base + i;
    if (idx < n){
      row_ptr[idx] = run;
      run += v[i];
      indeg[idx] = 0;
    }
    if (idx == n-1) row_ptr[n] = run;
  }
}

// ---------------- CSR fill + pre-scaled bf16 x0 conversion ----------
__global__ void k_fill_conv(const int* __restrict__ src, const int* __restrict__ dst,
                            const int* __restrict__ row_ptr, int* __restrict__ cursor,
                            int* __restrict__ col, int E_,
                            const float* __restrict__ x0,
                            const float* __restrict__ norm_s,
                            u32* __restrict__ x0bf, int n, int do_conv){
  int e = blockIdx.x*256 + threadIdx.x;
  if (e < E_){
    int d = dst[e];
    int pos = row_ptr[d] + atomicAdd(&cursor[d], 1);
    col[pos] = src[e];
  }
  if (do_conv){
    const int tot = n*48;
    if (e < tot){
      const int r = e/48, l = e - r*48;
      const int f0 = 2*l, f1 = 2*l + 1;
      const float ns = norm_s[r];
      const float u0 = (f0 < NODE_F) ? ns*x0[(size_t)r*NODE_F + f0] : 0.f;
      const float u1 = (f1 < NODE_F) ? ns*x0[(size_t)r*NODE_F + f1] : 0.f;
      x0bf[e] = packbf(u0, u1);
    }
  }
}

// ---------------- gather1b: 2 rows/wave from pre-scaled bf16 x0 [N][48] ------
__global__ __launch_bounds__(256, 8) void k_gather1b(
    const u32* __restrict__ x0bf, const int* __restrict__ row_ptr,
    const int* __restrict__ col, const float* __restrict__ norm_d,
    u32* __restrict__ ag1, int n){
  const int lane = threadIdx.x & 63;
  const int wv   = (blockIdx.x*256 + threadIdx.x) >> 6;
  const int r0   = wv*2;
  if (r0 >= n) return;
  int p[2], e[2];
  p[0] = row_ptr[r0]; e[0] = row_ptr[r0+1];
  const bool ok1 = (r0+1) < n;
  p[1] = ok1 ? e[0] : 0;
  e[1] = ok1 ? row_ptr[r0+2] : 0;
  const bool act = (lane < 48);
  const u32* xb = x0bf + lane;
  float a0[2] = {0.f,0.f}, a1[2] = {0.f,0.f};
  while ((p[0] < e[0]) | (p[1] < e[1])){
    int c[2], s[2][4];
    #pragma unroll
    for (int i = 0; i < 2; ++i){
      int d = e[i] - p[i];
      c[i] = (d > 4) ? 4 : ((d < 0) ? 0 : d);
      if (c[i] > 0){
        #pragma unroll
        for (int j = 0; j < 4; ++j)
          s[i][j] = col[p[i] + ((j < c[i]) ? j : (c[i]-1))];
      }
    }
    u32 v[2][4];
    #pragma unroll
    for (int i = 0; i < 2; ++i){
      #pragma unroll
      for (int j = 0; j < 4; ++j) v[i][j] = 0u;
      if (c[i] > 0 && act){
        #pragma unroll
        for (int j = 0; j < 4; ++j){
          const u32 t = xb[(size_t)s[i][j]*48];
          v[i][j] = (j < c[i]) ? t : 0u;
        }
      }
    }
    #pragma unroll
    for (int i = 0; i < 2; ++i){
      const float2 f0 = bfpair(v[i][0]), f1 = bfpair(v[i][1]);
      const float2 f2 = bfpair(v[i][2]), f3 = bfpair(v[i][3]);
      a0[i] += (f0.x + f1.x) + (f2.x + f3.x);
      a1[i] += (f0.y + f1.y) + (f2.y + f3.y);
      p[i] += c[i];
    }
  }
  if (lane < 48){
    #pragma unroll
    for (int i = 0; i < 2; ++i){
      const int row = r0 + i;
      if (row < n){
        const float nd = norm_d[row];
        ag1[(size_t)row*48 + lane] = packbf(a0[i]*nd, a1[i]*nd);
      }
    }
  }
}

// ---------------- gather2b: 2 rows/wave from bf16 h1 [N][128] ----------------
__global__ __launch_bounds__(256, 8) void k_gather2b(
    const u32* __restrict__ h1u, const int* __restrict__ row_ptr,
    const int* __restrict__ col, const float* __restrict__ norm_s,
    const float* __restrict__ norm_d, u32* __restrict__ ag2, int n){
  const int lane = threadIdx.x & 63;
  const int wv   = (blockIdx.x*256 + threadIdx.x) >> 6;
  const int r0   = wv*2;
  if (r0 >= n) return;
  int p[2], e[2];
  p[0] = row_ptr[r0]; e[0] = row_ptr[r0+1];
  const bool ok1 = (r0+1) < n;
  p[1] = ok1 ? e[0] : 0;
  e[1] = ok1 ? row_ptr[r0+2] : 0;
  const u32* hb = h1u + lane;
  float a0[2] = {0.f,0.f}, a1[2] = {0.f,0.f};
  while ((p[0] < e[0]) | (p[1] < e[1])){
    int c[2], s[2][4];
    #pragma unroll
    for (int i = 0; i < 2; ++i){
      int d = e[i] - p[i];
      c[i] = (d > 4) ? 4 : ((d < 0) ? 0 : d);
      if (c[i] > 0){
        #pragma unroll
        for (int j = 0; j < 4; ++j)
          s[i][j] = col[p[i] + ((j < c[i]) ? j : (c[i]-1))];
      }
    }
    float nw[2][4];
    u32 v[2][4];
    #pragma unroll
    for (int i = 0; i < 2; ++i){
      #pragma unroll
      for (int j = 0; j < 4; ++j){ nw[i][j] = 0.f; v[i][j] = 0u; }
      if (c[i] > 0){
        #pragma unroll
        for (int j = 0; j < 4; ++j) nw[i][j] = (j < c[i]) ? norm_s[s[i][j]] : 0.f;
        #pragma unroll
        for (int j = 0; j < 4; ++j) v[i][j] = hb[(size_t)s[i][j]*64];
      }
    }
    #pragma unroll
    for (int i = 0; i < 2; ++i){
      const float2 f0 = bfpair(v[i][0]), f1 = bfpair(v[i][1]);
      const float2 f2 = bfpair(v[i][2]), f3 = bfpair(v[i][3]);
      a0[i] = fmaf(f0.x, nw[i][0], fmaf(f1.x, nw[i][1],
              fmaf(f2.x, nw[i][2], fmaf(f3.x, nw[i][3], a0[i]))));
      a1[i] = fmaf(f0.y, nw[i][0], fmaf(f1.y, nw[i][1],
              fmaf(f2.y, nw[i][2], fmaf(f3.y, nw[i][3], a1[i]))));
      p[i] += c[i];
    }
  }
  #pragma unroll
  for (int i = 0; i < 2; ++i){
    const int row = r0 + i;
    if (row < n){
      const float nd = norm_d[row];
      ag2[(size_t)row*64 + lane] = packbf(a0[i]*nd, a1[i]*nd);
    }
  }
}

// ---------------- fallback gathers (round-7 proven, f32 x0) ------------------
__global__ __launch_bounds__(256) void k_gather1f(
    const float* __restrict__ x0, const int* __restrict__ row_ptr,
    const int* __restrict__ col, const float* __restrict__ norm_s,
    const float* __restrict__ norm_d, u32* __restrict__ ag1, int n){
  const int lane = threadIdx.x & 63;
  const int row  = blockIdx.x*4 + (threadIdx.x >> 6);
  if (row >= n) return;
  const int p0 = row_ptr[row], p1 = row_ptr[row+1];
  const bool act = (lane < 37);
  const float* xb = x0 + 2*lane;
  float a0 = 0.f, a1 = 0.f;
  int p = p0;
  #pragma unroll 1
  for (; p + 3 < p1; p += 4){
    const int s0 = col[p], s1 = col[p+1], s2 = col[p+2], s3 = col[p+3];
    const float n0 = norm_s[s0], n1 = norm_s[s1], n2 = norm_s[s2], n3 = norm_s[s3];
    float2 v0{0.f,0.f}, v1{0.f,0.f}, v2{0.f,0.f}, v3{0.f,0.f};
    if (act){
      v0 = *(const float2*)&xb[(size_t)s0*NODE_F];
      v1 = *(const float2*)&xb[(size_t)s1*NODE_F];
      v2 = *(const float2*)&xb[(size_t)s2*NODE_F];
      v3 = *(const float2*)&xb[(size_t)s3*NODE_F];
    }
    a0 = fmaf(v0.x,n0, fmaf(v1.x,n1, fmaf(v2.x,n2, fmaf(v3.x,n3, a0))));
    a1 = fmaf(v0.y,n0, fmaf(v1.y,n1, fmaf(v2.y,n2, fmaf(v3.y,n3, a1))));
  }
  const int rem = p1 - p;
  if (rem > 0){
    const int s0 = col[p];
    int s1 = s0, s2 = s0;
    float n1 = 0.f, n2 = 0.f;
    const float n0 = norm_s[s0];
    if (rem > 1){ s1 = col[p+1]; n1 = norm_s[s1]; }
    if (rem > 2){ s2 = col[p+2]; n2 = norm_s[s2]; }
    float2 v0{0.f,0.f}, v1{0.f,0.f}, v2{0.f,0.f};
    if (act){
      v0 = *(const float2*)&xb[(size_t)s0*NODE_F];
      v1 = *(const float2*)&xb[(size_t)s1*NODE_F];
      v2 = *(const float2*)&xb[(size_t)s2*NODE_F];
    }
    a0 = fmaf(v0.x,n0, fmaf(v1.x,n1, fmaf(v2.x,n2, a0)));
    a1 = fmaf(v0.y,n0, fmaf(v1.y,n1, fmaf(v2.y,n2, a1)));
  }
  if (lane < 48){
    const float nd = norm_d[row];
    ag1[(size_t)row*48 + lane] = packbf(a0*nd, a1*nd);
  }
}

__global__ __launch_bounds__(256) void k_gather2f(
    const u32* __restrict__ h1u, const int* __restrict__ row_ptr,
    const int* __restrict__ col, const float* __restrict__ norm_s,
    const float* __restrict__ norm_d, u32* __restrict__ ag2, int n){
  const int lane = threadIdx.x & 63;
  const int row  = blockIdx.x*4 + (threadIdx.x >> 6);
  if (row >= n) return;
  const int p0 = row_ptr[row], p1 = row_ptr[row+1];
  const u32* hb = h1u + lane;
  float a0 = 0.f, a1 = 0.f;
  int p = p0;
  #pragma unroll 1
  for (; p + 3 < p1; p += 4){
    const int s0 = col[p], s1 = col[p+1], s2 = col[p+2], s3 = col[p+3];
    const float n0 = norm_s[s0], n1 = norm_s[s1], n2 = norm_s[s2], n3 = norm_s[s3];
    const u32 u0 = hb[(size_t)s0*64];
    const u32 u1 = hb[(size_t)s1*64];
    const u32 u2 = hb[(size_t)s2*64];
    const u32 u3 = hb[(size_t)s3*64];
    const float2 f0 = bfpair(u0), f1 = bfpair(u1), f2 = bfpair(u2), f3 = bfpair(u3);
    a0 = fmaf(f0.x,n0, fmaf(f1.x,n1, fmaf(f2.x,n2, fmaf(f3.x,n3, a0))));
    a1 = fmaf(f0.y,n0, fmaf(f1.y,n1, fmaf(f2.y,n2, fmaf(f3.y,n3, a1))));
  }
  const int rem = p1 - p;
  if (rem > 0){
    const int s0 = col[p];
    int s1 = s0, s2 = s0;
    float n1 = 0.f, n2 = 0.f;
    const float n0 = norm_s[s0];
    if (rem > 1){ s1 = col[p+1]; n1 = norm_s[s1]; }
    if (rem > 2){ s2 = col[p+2]; n2 = norm_s[s2]; }
    const u32 u0 = hb[(size_t)s0*64];
    const u32 u1 = hb[(size_t)s1*64];
    const u32 u2 = hb[(size_t)s2*64];
    const float2 f0 = bfpair(u0), f1 = bfpair(u1), f2 = bfpair(u2);
    a0 = fmaf(f0.x,n0, fmaf(f1.x,n1, fmaf(f2.x,n2, a0)));
    a1 = fmaf(f0.y,n0, fmaf(f1.y,n1, fmaf(f2.y,n2, a1)));
  }
  const float nd = norm_d[row];
  ag2[(size_t)row*64 + lane] = packbf(a0*nd, a1*nd);
}

// ---------------- dense GEMM layer1 (LDS-staged B, persistent tiles) ---------
__global__ __launch_bounds__(256) void k_ggemm1(
    const u16* __restrict__ ag1, const float* __restrict__ x0,
    const u16* __restrict__ Bp, const float* __restrict__ bg_,
    const float* __restrict__ br_, u16* __restrict__ h1, int n){
  constexpr int FR1 = 8*3*512;                 // 12288 u16 per matrix
  __shared__ __align__(16) u16 sB[2*FR1];      // 48 KB
  {
    const uint4* s4 = (const uint4*)Bp;
    uint4* d4 = (uint4*)sB;
    #pragma unroll
    for (int i = 0; i < 12; ++i)
      d4[threadIdx.x + i*256] = s4[threadIdx.x + i*256];   // 2*FR1/8 = 3072
  }
  __syncthreads();
  const int lane = threadIdx.x & 63;
  const int wid  = threadIdx.x >> 6;
  const int jg = lane & 15, kg = lane >> 4;
  const int kb = kg*8;
  const int nb = (n + 63) >> 6;
  for (int bt = blockIdx.x; bt < nb; bt += gridDim.x){
    const int r0 = bt*64 + wid*16;
    if (r0 >= n) continue;
    const int row = r0 + jg;
    const bool rok = row < n;
    const int rA = rok ? row : (n-1);

    bf16x8 ag[3], ar[3];
    #pragma unroll
    for (int s = 0; s < 3; ++s)
      ag[s] = __builtin_bit_cast(bf16x8, *(const s16x8*)&ag1[(size_t)rA*96 + s*32 + kb]);
    {
      const float* px = x0 + (size_t)rA*NODE_F;
      #pragma unroll
      for (int s = 0; s < 2; ++s)
        #pragma unroll
        for (int e = 0; e < 8; e += 2){
          const float2 w = *(const float2*)&px[s*32 + kb + e];
          ar[s][e]   = (__bf16)w.x;
          ar[s][e+1] = (__bf16)w.y;
        }
      #pragma unroll
      for (int e = 0; e < 8; ++e) ar[2][e] = (__bf16)0.f;
      if (kg == 0){
        #pragma unroll
        for (int e = 0; e < 8; e += 2){
          const float2 w = *(const float2*)&px[64 + e];
          ar[2][e]   = (__bf16)w.x;
          ar[2][e+1] = (__bf16)w.y;
        }
      } else if (kg == 1){
        const float2 w = *(const float2*)&px[72];
        ar[2][0] = (__bf16)w.x;
        ar[2][1] = (__bf16)w.y;
      }
    }

    f32x4 accg[8], accr[8];
    #pragma unroll
    for (int t = 0; t < 8; ++t){
      accg[t] = f32x4{0.f,0.f,0.f,0.f};
      accr[t] = f32x4{0.f,0.f,0.f,0.f};
    }
    #pragma unroll
    for (int s = 0; s < 3; ++s){
      #pragma unroll
      for (int t = 0; t < 8; ++t){
        const bf16x8 bg = __builtin_bit_cast(bf16x8,
            *(const s16x8*)&sB[((t*3 + s)*64 + lane)*8]);
        const bf16x8 br = __builtin_bit_cast(bf16x8,
            *(const s16x8*)&sB[FR1 + ((t*3 + s)*64 + lane)*8]);
        accg[t] = __builtin_amdgcn_mfma_f32_16x16x32_bf16(ag[s], bg, accg[t], 0,0,0);
        accr[t] = __builtin_amdgcn_mfma_f32_16x16x32_bf16(ar[s], br, accr[t], 0,0,0);
      }
    }

    const int rowb = r0 + 4*kg;
    #pragma unroll
    for (int t = 0; t < 8; ++t){
      const int colc = t*16 + jg;
      const float bgv = bg_[colc], brv = br_[colc];
      #pragma unroll
      for (int r = 0; r < 4; ++r){
        const int row2 = rowb + r;
        if (row2 < n){
          const float o = fmaxf(accg[t][r] + bgv, 0.f) + fmaxf(accr[t][r] + brv, 0.f);
          h1[(size_t)row2*HID + colc] = bfbits(o);
        }
      }
    }
  }
}

// ---------------- dense GEMM layer2 + fused readout (LDS-staged B) -----------
__global__ __launch_bounds__(256) void k_ggemm2(
    const u16* __restrict__ ag2, const u16* __restrict__ h1,
    const u16* __restrict__ Bp, const float* __restrict__ bg_,
    const float* __restrict__ br_,
    const float* __restrict__ w_atom, const float* __restrict__ b_atom,
    const int* __restrict__ gid,
    float* __restrict__ hsum, u32* __restrict__ hmax, int n){
  constexpr int FR2 = 8*4*512;                 // 16384 u16 per matrix
  __shared__ __align__(16) u16 sB[2*FR2];      // 64 KB
  {
    const uint4* s4 = (const uint4*)Bp;
    uint4* d4 = (uint4*)sB;
    #pragma unroll
    for (int i = 0; i < 16; ++i)
      d4[threadIdx.x + i*256] = s4[threadIdx.x + i*256];   // 2*FR2/8 = 4096
  }
  __syncthreads();
  const int lane = threadIdx.x & 63;
  const int wid  = threadIdx.x >> 6;
  const int jg = lane & 15, kg = lane >> 4;
  const int kb = kg*8;
  const int nb = (n + 63) >> 6;
  for (int bt = blockIdx.x; bt < nb; bt += gridDim.x){
    const int r0 = bt*64 + wid*16;
    if (r0 >= n) continue;
    const int row = r0 + jg;
    const bool rok = row < n;
    const int rA = rok ? row : (n-1);

    f32x4 accg[8], accr[8];
    #pragma unroll
    for (int t = 0; t < 8; ++t){
      accg[t] = f32x4{0.f,0.f,0.f,0.f};
      accr[t] = f32x4{0.f,0.f,0.f,0.f};
    }
    #pragma unroll
    for (int s = 0; s < 4; ++s){
      const bf16x8 agf = __builtin_bit_cast(bf16x8,
          *(const s16x8*)&ag2[(size_t)rA*HID + s*32 + kb]);
      const bf16x8 arf = __builtin_bit_cast(bf16x8,
          *(const s16x8*)&h1[(size_t)rA*HID + s*32 + kb]);
      #pragma unroll
      for (int t = 0; t < 8; ++t){
        const bf16x8 bg = __builtin_bit_cast(bf16x8,
            *(const s16x8*)&sB[((t*4 + s)*64 + lane)*8]);
        const bf16x8 br = __builtin_bit_cast(bf16x8,
            *(const s16x8*)&sB[FR2 + ((t*4 + s)*64 + lane)*8]);
        accg[t] = __builtin_amdgcn_mfma_f32_16x16x32_bf16(agf, bg, accg[t], 0,0,0);
        accr[t] = __builtin_amdgcn_mfma_f32_16x16x32_bf16(arf, br, accr[t], 0,0,0);
      }
    }

    float o[8][4];
    #pragma unroll
    for (int t = 0; t < 8; ++t){
      const int colc = t*16 + jg;
      const float bgv = bg_[colc], brv = br_[colc];
      #pragma unroll
      for (int r = 0; r < 4; ++r)
        o[t][r] = fmaxf(accg[t][r] + bgv, 0.f) + fmaxf(accr[t][r] + brv, 0.f);
    }
    float wa[8];
    #pragma unroll
    for (int t = 0; t < 8; ++t) wa[t] = w_atom[t*16 + jg];
    const float ba = b_atom[0];
    const int rowb = r0 + 4*kg;
    float awv[4]; int gidr[4];
    #pragma unroll
    for (int r = 0; r < 4; ++r){
      const int row2 = rowb + r;
      float dot = 0.f;
      #pragma unroll
      for (int t = 0; t < 8; ++t) dot = fmaf(o[t][r], wa[t], dot);
      dot += __shfl_xor(dot, 1);
      dot += __shfl_xor(dot, 2);
      dot += __shfl_xor(dot, 4);
      dot += __shfl_xor(dot, 8);
      awv[r]  = 1.0f/(1.0f + __expf(-(dot + ba)));
      gidr[r] = (row2 < n) ? gid[row2] : -1;
    }
    const int rhi    = (r0 + 15 < n) ? (r0 + 15) : (n - 1);
    const int gfirst = gid[r0];
    const int glast  = gid[rhi];
    for (int g = gfirst; g <= glast; ++g){
      #pragma unroll
      for (int t = 0; t < 8; ++t){
        float sv = 0.f, mv = 0.f;
        #pragma unroll
        for (int r = 0; r < 4; ++r){
          const bool in = (gidr[r] == g);
          sv += in ? o[t][r]*awv[r] : 0.f;
          mv  = in ? fmaxf(mv, o[t][r]) : mv;
        }
        sv += __shfl_xor(sv, 16);
        sv += __shfl_xor(sv, 32);
        mv  = fmaxf(mv, __shfl_xor(mv, 16));
        mv  = fmaxf(mv, __shfl_xor(mv, 32));
        if (lane < 16){
          atomicAdd(&hsum[(size_t)g*HID + t*16 + jg], sv);
          atomicMax(&hmax[(size_t)g*HID + t*16 + jg], __float_as_uint(mv));  // o >= 0
        }
      }
    }
  }
}

// ---------------- fused MLP: latent = relu(gfeat@Wp1+bp1)@Wp2+bp2, zero-row insert
__global__ __launch_bounds__(256) void k_mlp(
    const float* __restrict__ hsum, const float* __restrict__ hmaxf,
    const float* __restrict__ Wp1, const float* __restrict__ bp1,
    const float* __restrict__ Wp2, const float* __restrict__ bp2,
    const int* __restrict__ idxw, int K_,
    float* __restrict__ out, int G_){
  const int lane = threadIdx.x & 63;
  const int row = blockIdx.x*4 + (threadIdx.x >> 6);
  if (blockIdx.x == 0){
    for (int j = 0; j < K_; ++j){
      const int zr = idxw[j];
      for (int i = threadIdx.x; i < DIM; i += 256)
        out[(size_t)zr*DIM + i] = 0.f;
    }
  }
  if (row >= G_) return;
  const int c = lane*2;
  float ra0 = hsum [(size_t)row*HID + lane];
  float ra1 = hsum [(size_t)row*HID + 64 + lane];
  float ra2 = hmaxf[(size_t)row*HID + lane];
  float ra3 = hmaxf[(size_t)row*HID + 64 + lane];
  float a0 = 0.f, a1 = 0.f;
  #pragma unroll 4
  for (int k = 0; k < 64; ++k){
    const float v0 = rdl(ra0,k), v1 = rdl(ra1,k), v2 = rdl(ra2,k), v3 = rdl(ra3,k);
    const float2 w0 = *(const float2*)&Wp1[(size_t)(k      )*HID + c];
    const float2 w1 = *(const float2*)&Wp1[(size_t)(k +  64)*HID + c];
    const float2 w2 = *(const float2*)&Wp1[(size_t)(k + 128)*HID + c];
    const float2 w3 = *(const float2*)&Wp1[(size_t)(k + 192)*HID + c];
    a0 = fmaf(v0,w0.x, fmaf(v1,w1.x, fmaf(v2,w2.x, fmaf(v3,w3.x, a0))));
    a1 = fmaf(v0,w0.y, fmaf(v1,w1.y, fmaf(v2,w2.y, fmaf(v3,w3.y, a1))));
  }
  const float h0  = fmaxf(a0 + bp1[c],   0.f);
  const float h1v = fmaxf(a1 + bp1[c+1], 0.f);
  const int c4 = lane*4;
  float acc0=0.f, acc1=0.f, acc2=0.f, acc3=0.f;
  #pragma unroll 4
  for (int j = 0; j < 64; ++j){
    const float he = rdl(h0, j);
    const float ho = rdl(h1v, j);
    const float4 we = *(const float4*)&Wp2[(size_t)(2*j  )*DIM + c4];
    const float4 wo = *(const float4*)&Wp2[(size_t)(2*j+1)*DIM + c4];
    acc0 = fmaf(he,we.x, fmaf(ho,wo.x, acc0));
    acc1 = fmaf(he,we.y, fmaf(ho,wo.y, acc1));
    acc2 = fmaf(he,we.z, fmaf(ho,wo.z, acc2));
    acc3 = fmaf(he,we.w, fmaf(ho,wo.w, acc3));
  }
  int orow = row;
  for (int j = 0; j < K_; ++j){ if (idxw[j] <= orow) orow++; }
  float* po = out + (size_t)orow*DIM + c4;
  po[0] = acc0 + bp2[c4];
  po[1] = acc1 + bp2[c4+1];
  po[2] = acc2 + bp2[c4+2];
  po[3] = acc3 + bp2[c4+3];
}

extern "C" void kernel_launch(void* const* d_in, const int* in_sizes, int n_in,
                              void* d_out, int out_size, void* d_ws, size_t ws_size,
                              hipStream_t stream){
  (void)n_in;
  const float* x0     = (const float*)d_in[0];
  const float* W1     = (const float*)d_in[2];
  const float* b1     = (const float*)d_in[3];
  const float* Wr1    = (const float*)d_in[4];
  const float* br1    = (const float*)d_in[5];
  const float* W2     = (const float*)d_in[6];
  const float* b2     = (const float*)d_in[7];
  const float* Wr2    = (const float*)d_in[8];
  const float* br2    = (const float*)d_in[9];
  const float* w_atom = (const float*)d_in[10];
  const float* b_atom = (const float*)d_in[11];
  const float* Wp1    = (const float*)d_in[12];
  const float* bp1    = (const float*)d_in[13];
  const float* Wp2    = (const float*)d_in[14];
  const float* bp2    = (const float*)d_in[15];
  const int* src  = (const int*)d_in[16];
  const int* dst  = (const int*)d_in[17];
  const int* gid  = (const int*)d_in[18];
  const int* idxw = (const int*)d_in[19];

  const int N_ = in_sizes[0] / NODE_F;
  const int E_ = in_sizes[16];
  const int K_ = in_sizes[19];
  const int G_ = out_size / DIM - K_;

  // workspace (proven layout, rounds 8-9):
  u16*   h1     = (u16*)d_ws;
  float* norm_d = (float*)(h1 + (size_t)N_*HID);
  float* norm_s = norm_d + N_;
  float* hsum   = norm_s + N_;
  float* hmaxv  = hsum + (size_t)G_*HID;
  int*   indeg  = (int*)(hmaxv + (size_t)G_*HID);
  int*   row_ptr= indeg + N_;
  int*   col    = row_ptr + ((N_ + 4) & ~3);
  int*   bsum   = col + ((E_ + 4) & ~3);
  const int nscan = (N_ + 1023)/1024;
  uintptr_t aggp = ((uintptr_t)(bsum + nscan) + 255) & ~(uintptr_t)255;
  u32* aggu = (u32*)aggp;                              // [N][64] u32 (25.6 MB)
  uintptr_t x0bfp = aggp + (size_t)N_*64*sizeof(u32);
  u32* x0bf = (u32*)x0bfp;                             // [N][48] u32 (19.2 MB)
  const size_t need_bf = (x0bfp + (size_t)N_*48*sizeof(u32)) - (uintptr_t)d_ws;
  const bool use_bf = (ws_size >= need_bf);

  // weight-fragment scratch in d_out (112 KB; fully overwritten by k_mlp later)
  u16*   Bp1    = (u16*)d_out;                         // 2*12288 u16
  u16*   Bp2    = Bp1 + 2*12288;                       // 2*16384 u16

  hipMemsetAsync(norm_s, 0, ((size_t)2*N_ + (size_t)2*G_*HID)*sizeof(float), stream);

  k_deg_prep<<<(E_+255)/256, 256, 0, stream>>>(src, dst, norm_s, indeg, E_,
                                               W1, Wr1, W2, Wr2, Bp1, Bp2);
  k_scan_a  <<<nscan, 256, 0, stream>>>(indeg, norm_s, norm_d, bsum, N_);
  k_scan_b  <<<1, 1024, 0, stream>>>(bsum, nscan);
  k_scan_c  <<<nscan, 256, 0, stream>>>(indeg, bsum, row_ptr, N_);

  const int conv_tot = use_bf ? (N_*48 > E_ ? N_*48 : E_) : E_;
  k_fill_conv<<<(conv_tot+255)/256, 256, 0, stream>>>(
      src, dst, row_ptr, indeg, col, E_, x0, norm_s,
      use_bf ? x0bf : aggu, N_, use_bf ? 1 : 0);

  const int nb   = (N_ + 63) / 64;
  const int nbw  = (N_ + 3) / 4;     // fallback: 1 row/wave
  const int nbw2 = (N_ + 7) / 8;     // 2 rows/wave, 4 waves/block
  const int g1   = (nb < 768) ? nb : 768;   // 3 blocks/CU at 48 KB LDS
  const int g2   = (nb < 512) ? nb : 512;   // 2 blocks/CU at 64 KB LDS
  if (use_bf){
    k_gather1b<<<nbw2, 256, 0, stream>>>(x0bf, row_ptr, col, norm_d, aggu, N_);
  } else {
    k_gather1f<<<nbw, 256, 0, stream>>>(x0, row_ptr, col, norm_s, norm_d, aggu, N_);
  }
  k_ggemm1<<<g1, 256, 0, stream>>>((const u16*)aggu, x0, Bp1, b1, br1, h1, N_);
  if (use_bf){
    k_gather2b<<<nbw2, 256, 0, stream>>>((const u32*)h1, row_ptr, col, norm_s,
                                         norm_d, aggu, N_);
  } else {
    k_gather2f<<<nbw, 256, 0, stream>>>((const u32*)h1, row_ptr, col, norm_s,
                                        norm_d, aggu, N_);
  }
  k_ggemm2<<<g2, 256, 0, stream>>>((const u16*)aggu, h1, Bp2, b2, br2,
                                   w_atom, b_atom, gid, hsum, (u32*)hmaxv, N_);

  k_mlp<<<(G_+3)/4, 256, 0, stream>>>(hsum, hmaxv, Wp1, bp1, Wp2, bp2,
                                      idxw, K_, (float*)d_out, G_);
}

// Round 11
// 335.077 us; speedup vs baseline: 1.1602x; 1.0080x over previous
//
#include <hip/hip_runtime.h>
#include <hip/hip_bf16.h>
#include <stdint.h>

#define NODE_F 74
#define HID 128
#define DIM 256

typedef __hip_bfloat16 bf16;
typedef unsigned int u32;
typedef unsigned short u16;

typedef short s16x8 __attribute__((ext_vector_type(8)));
typedef __bf16 bf16x8 __attribute__((ext_vector_type(8)));
typedef float f32x4 __attribute__((ext_vector_type(4)));

__device__ __forceinline__ float rdl(float v, int l){
  return __int_as_float(__builtin_amdgcn_readlane(__float_as_int(v), l));
}
__device__ __forceinline__ float2 bfpair(u32 u){
  float2 r;
  r.x = __uint_as_float(u << 16);
  r.y = __uint_as_float(u & 0xffff0000u);
  return r;
}
__device__ __forceinline__ u32 packbf(float a, float b){
  u32 lo = (u32)__bfloat16_as_ushort(__float2bfloat16(a));
  u32 hi = (u32)__bfloat16_as_ushort(__float2bfloat16(b));
  return lo | (hi << 16);
}
__device__ __forceinline__ u16 bfbits(float a){
  return __bfloat16_as_ushort(__float2bfloat16(a));
}

// ---------------- degrees + weight prepack (merged) ----------------
__global__ void k_deg_prep(const int* __restrict__ src, const int* __restrict__ dst_,
                           float* __restrict__ outdeg_f, int* __restrict__ indeg, int E_,
                           const float* __restrict__ W1, const float* __restrict__ Wr1,
                           const float* __restrict__ W2, const float* __restrict__ Wr2,
                           u16* __restrict__ Bp1, u16* __restrict__ Bp2){
  int e = blockIdx.x*256 + threadIdx.x;
  if (e < E_){
    atomicAdd(&outdeg_f[src[e]], 1.0f);
    atomicAdd(&indeg[dst_[e]], 1);
  }
  int idx = e;
  if (idx < 57344){
    const float* W; u16* dstp; int S, Ktrue, loc;
    if      (idx < 12288){ W = W1;  dstp = Bp1;          S = 3; Ktrue = NODE_F; loc = idx; }
    else if (idx < 24576){ W = Wr1; dstp = Bp1 + 12288;  S = 3; Ktrue = NODE_F; loc = idx - 12288; }
    else if (idx < 40960){ W = W2;  dstp = Bp2;          S = 4; Ktrue = HID;    loc = idx - 24576; }
    else                 { W = Wr2; dstp = Bp2 + 16384;  S = 4; Ktrue = HID;    loc = idx - 40960; }
    const int el  = loc & 7;
    const int l   = (loc >> 3) & 63;
    const int rem = loc >> 9;
    const int s   = rem % S;
    const int t   = rem / S;
    const int k   = s*32 + (l >> 4)*8 + el;
    const int c   = t*16 + (l & 15);
    const float v = (k < Ktrue) ? W[(size_t)k*HID + c] : 0.f;
    dstp[loc] = bfbits(v);
  }
}

// ---------------- CSR build: 3-phase device-wide exclusive scan ----------------
__global__ __launch_bounds__(256) void k_scan_a(const int* __restrict__ indeg,
                                                float* __restrict__ norm_s,
                                                float* __restrict__ norm_d,
                                                int* __restrict__ bsum, int n){
  __shared__ int red[256];
  const int base = blockIdx.x*1024 + threadIdx.x*4;
  int s = 0;
  #pragma unroll
  for (int i = 0; i < 4; ++i){
    const int idx = base + i;
    if (idx < n){
      const int d = indeg[idx];
      s += d;
      norm_d[idx] = rsqrtf(fmaxf((float)d, 1.0f));
      norm_s[idx] = rsqrtf(fmaxf(norm_s[idx], 1.0f));
    }
  }
  red[threadIdx.x] = s;
  __syncthreads();
  #pragma unroll
  for (int off = 128; off; off >>= 1){
    if (threadIdx.x < off) red[threadIdx.x] += red[threadIdx.x + off];
    __syncthreads();
  }
  if (threadIdx.x == 0) bsum[blockIdx.x] = red[0];
}

__global__ __launch_bounds__(1024) void k_scan_b(int* __restrict__ bsum, int nb){
  __shared__ int part[1024];
  __shared__ int carry;
  if (threadIdx.x == 0) carry = 0;
  __syncthreads();
  for (int c0 = 0; c0 < nb; c0 += 1024){
    const int tid = threadIdx.x, idx = c0 + tid;
    part[tid] = (idx < nb) ? bsum[idx] : 0;
    __syncthreads();
    for (int off = 1; off < 1024; off <<= 1){
      const int t = (tid >= off) ? part[tid-off] : 0;
      __syncthreads();
      part[tid] += t;
      __syncthreads();
    }
    if (idx < nb) bsum[idx] = carry + ((tid == 0) ? 0 : part[tid-1]);
    __syncthreads();
    if (tid == 0) carry += part[1023];
    __syncthreads();
  }
}

__global__ __launch_bounds__(256) void k_scan_c(int* __restrict__ indeg,
                                                const int* __restrict__ bsum,
                                                int* __restrict__ row_ptr, int n){
  __shared__ int part[256];
  const int base = blockIdx.x*1024 + threadIdx.x*4;
  int v[4]; int s = 0;
  #pragma unroll
  for (int i = 0; i < 4; ++i){
    const int idx = base + i;
    v[i] = (idx < n) ? indeg[idx] : 0;
    s += v[i];
  }
  part[threadIdx.x] = s;
  __syncthreads();
  for (int off = 1; off < 256; off <<= 1){
    const int t = (threadIdx.x >= off) ? part[threadIdx.x-off] : 0;
    __syncthreads();
    part[threadIdx.x] += t;
    __syncthreads();
  }
  int run = bsum[blockIdx.x] + ((threadIdx.x == 0) ? 0 : part[threadIdx.x-1]);
  #pragma unroll
  for (int i = 0; i < 4; ++i){
    const int idx = base + i;
    if (idx < n){
      row_ptr[idx] = run;
      run += v[i];
      indeg[idx] = 0;
    }
    if (idx == n-1) row_ptr[n] = run;
  }
}

// ---------------- CSR fill + pre-scaled bf16 x0 conversion ----------
__global__ void k_fill_conv(const int* __restrict__ src, const int* __restrict__ dst,
                            const int* __restrict__ row_ptr, int* __restrict__ cursor,
                            int* __restrict__ col, int E_,
                            const float* __restrict__ x0,
                            const float* __restrict__ norm_s,
                            u32* __restrict__ x0bf, int n, int do_conv){
  int e = blockIdx.x*256 + threadIdx.x;
  if (e < E_){
    int d = dst[e];
    int pos = row_ptr[d] + atomicAdd(&cursor[d], 1);
    col[pos] = src[e];
  }
  if (do_conv){
    const int tot = n*48;
    if (e < tot){
      const int r = e/48, l = e - r*48;
      const int f0 = 2*l, f1 = 2*l + 1;
      const float ns = norm_s[r];
      const float u0 = (f0 < NODE_F) ? ns*x0[(size_t)r*NODE_F + f0] : 0.f;
      const float u1 = (f1 < NODE_F) ? ns*x0[(size_t)r*NODE_F + f1] : 0.f;
      x0bf[e] = packbf(u0, u1);
    }
  }
}

// ---------------- gather1b: 2 rows/wave from pre-scaled bf16 x0 [N][48] ------
__global__ __launch_bounds__(256, 8) void k_gather1b(
    const u32* __restrict__ x0bf, const int* __restrict__ row_ptr,
    const int* __restrict__ col, const float* __restrict__ norm_d,
    u32* __restrict__ ag1, int n){
  const int lane = threadIdx.x & 63;
  const int wv   = (blockIdx.x*256 + threadIdx.x) >> 6;
  const int r0   = wv*2;
  if (r0 >= n) return;
  int p[2], e[2];
  p[0] = row_ptr[r0]; e[0] = row_ptr[r0+1];
  const bool ok1 = (r0+1) < n;
  p[1] = ok1 ? e[0] : 0;
  e[1] = ok1 ? row_ptr[r0+2] : 0;
  const bool act = (lane < 48);
  const u32* xb = x0bf + lane;
  float a0[2] = {0.f,0.f}, a1[2] = {0.f,0.f};
  while ((p[0] < e[0]) | (p[1] < e[1])){
    int c[2], s[2][4];
    #pragma unroll
    for (int i = 0; i < 2; ++i){
      int d = e[i] - p[i];
      c[i] = (d > 4) ? 4 : ((d < 0) ? 0 : d);
      if (c[i] > 0){
        #pragma unroll
        for (int j = 0; j < 4; ++j)
          s[i][j] = col[p[i] + ((j < c[i]) ? j : (c[i]-1))];
      }
    }
    u32 v[2][4];
    #pragma unroll
    for (int i = 0; i < 2; ++i){
      #pragma unroll
      for (int j = 0; j < 4; ++j) v[i][j] = 0u;
      if (c[i] > 0 && act){
        #pragma unroll
        for (int j = 0; j < 4; ++j){
          const u32 t = xb[(size_t)s[i][j]*48];
          v[i][j] = (j < c[i]) ? t : 0u;
        }
      }
    }
    #pragma unroll
    for (int i = 0; i < 2; ++i){
      const float2 f0 = bfpair(v[i][0]), f1 = bfpair(v[i][1]);
      const float2 f2 = bfpair(v[i][2]), f3 = bfpair(v[i][3]);
      a0[i] += (f0.x + f1.x) + (f2.x + f3.x);
      a1[i] += (f0.y + f1.y) + (f2.y + f3.y);
      p[i] += c[i];
    }
  }
  if (lane < 48){
    #pragma unroll
    for (int i = 0; i < 2; ++i){
      const int row = r0 + i;
      if (row < n){
        const float nd = norm_d[row];
        ag1[(size_t)row*48 + lane] = packbf(a0[i]*nd, a1[i]*nd);
      }
    }
  }
}

// ---------------- gather2s: 2 rows/wave from pre-scaled bf16 h1s [N][128] ----
__global__ __launch_bounds__(256, 8) void k_gather2s(
    const u32* __restrict__ h1su, const int* __restrict__ row_ptr,
    const int* __restrict__ col, const float* __restrict__ norm_d,
    u32* __restrict__ ag2, int n){
  const int lane = threadIdx.x & 63;
  const int wv   = (blockIdx.x*256 + threadIdx.x) >> 6;
  const int r0   = wv*2;
  if (r0 >= n) return;
  int p[2], e[2];
  p[0] = row_ptr[r0]; e[0] = row_ptr[r0+1];
  const bool ok1 = (r0+1) < n;
  p[1] = ok1 ? e[0] : 0;
  e[1] = ok1 ? row_ptr[r0+2] : 0;
  const u32* hb = h1su + lane;
  float a0[2] = {0.f,0.f}, a1[2] = {0.f,0.f};
  while ((p[0] < e[0]) | (p[1] < e[1])){
    int c[2], s[2][4];
    #pragma unroll
    for (int i = 0; i < 2; ++i){
      int d = e[i] - p[i];
      c[i] = (d > 4) ? 4 : ((d < 0) ? 0 : d);
      if (c[i] > 0){
        #pragma unroll
        for (int j = 0; j < 4; ++j)
          s[i][j] = col[p[i] + ((j < c[i]) ? j : (c[i]-1))];
      }
    }
    u32 v[2][4];
    #pragma unroll
    for (int i = 0; i < 2; ++i){
      #pragma unroll
      for (int j = 0; j < 4; ++j) v[i][j] = 0u;
      if (c[i] > 0){
        #pragma unroll
        for (int j = 0; j < 4; ++j){
          const u32 t = hb[(size_t)s[i][j]*64];
          v[i][j] = (j < c[i]) ? t : 0u;
        }
      }
    }
    #pragma unroll
    for (int i = 0; i < 2; ++i){
      const float2 f0 = bfpair(v[i][0]), f1 = bfpair(v[i][1]);
      const float2 f2 = bfpair(v[i][2]), f3 = bfpair(v[i][3]);
      a0[i] += (f0.x + f1.x) + (f2.x + f3.x);
      a1[i] += (f0.y + f1.y) + (f2.y + f3.y);
      p[i] += c[i];
    }
  }
  #pragma unroll
  for (int i = 0; i < 2; ++i){
    const int row = r0 + i;
    if (row < n){
      const float nd = norm_d[row];
      ag2[(size_t)row*64 + lane] = packbf(a0[i]*nd, a1[i]*nd);
    }
  }
}

// ---------------- gather2b: fallback, 2 rows/wave, unscaled h1 ----------------
__global__ __launch_bounds__(256, 8) void k_gather2b(
    const u32* __restrict__ h1u, const int* __restrict__ row_ptr,
    const int* __restrict__ col, const float* __restrict__ norm_s,
    const float* __restrict__ norm_d, u32* __restrict__ ag2, int n){
  const int lane = threadIdx.x & 63;
  const int wv   = (blockIdx.x*256 + threadIdx.x) >> 6;
  const int r0   = wv*2;
  if (r0 >= n) return;
  int p[2], e[2];
  p[0] = row_ptr[r0]; e[0] = row_ptr[r0+1];
  const bool ok1 = (r0+1) < n;
  p[1] = ok1 ? e[0] : 0;
  e[1] = ok1 ? row_ptr[r0+2] : 0;
  const u32* hb = h1u + lane;
  float a0[2] = {0.f,0.f}, a1[2] = {0.f,0.f};
  while ((p[0] < e[0]) | (p[1] < e[1])){
    int c[2], s[2][4];
    #pragma unroll
    for (int i = 0; i < 2; ++i){
      int d = e[i] - p[i];
      c[i] = (d > 4) ? 4 : ((d < 0) ? 0 : d);
      if (c[i] > 0){
        #pragma unroll
        for (int j = 0; j < 4; ++j)
          s[i][j] = col[p[i] + ((j < c[i]) ? j : (c[i]-1))];
      }
    }
    float nw[2][4];
    u32 v[2][4];
    #pragma unroll
    for (int i = 0; i < 2; ++i){
      #pragma unroll
      for (int j = 0; j < 4; ++j){ nw[i][j] = 0.f; v[i][j] = 0u; }
      if (c[i] > 0){
        #pragma unroll
        for (int j = 0; j < 4; ++j) nw[i][j] = (j < c[i]) ? norm_s[s[i][j]] : 0.f;
        #pragma unroll
        for (int j = 0; j < 4; ++j) v[i][j] = hb[(size_t)s[i][j]*64];
      }
    }
    #pragma unroll
    for (int i = 0; i < 2; ++i){
      const float2 f0 = bfpair(v[i][0]), f1 = bfpair(v[i][1]);
      const float2 f2 = bfpair(v[i][2]), f3 = bfpair(v[i][3]);
      a0[i] = fmaf(f0.x, nw[i][0], fmaf(f1.x, nw[i][1],
              fmaf(f2.x, nw[i][2], fmaf(f3.x, nw[i][3], a0[i]))));
      a1[i] = fmaf(f0.y, nw[i][0], fmaf(f1.y, nw[i][1],
              fmaf(f2.y, nw[i][2], fmaf(f3.y, nw[i][3], a1[i]))));
      p[i] += c[i];
    }
  }
  #pragma unroll
  for (int i = 0; i < 2; ++i){
    const int row = r0 + i;
    if (row < n){
      const float nd = norm_d[row];
      ag2[(size_t)row*64 + lane] = packbf(a0[i]*nd, a1[i]*nd);
    }
  }
}

// ---------------- fallback gathers (round-7 proven, f32 x0) ------------------
__global__ __launch_bounds__(256) void k_gather1f(
    const float* __restrict__ x0, const int* __restrict__ row_ptr,
    const int* __restrict__ col, const float* __restrict__ norm_s,
    const float* __restrict__ norm_d, u32* __restrict__ ag1, int n){
  const int lane = threadIdx.x & 63;
  const int row  = blockIdx.x*4 + (threadIdx.x >> 6);
  if (row >= n) return;
  const int p0 = row_ptr[row], p1 = row_ptr[row+1];
  const bool act = (lane < 37);
  const float* xb = x0 + 2*lane;
  float a0 = 0.f, a1 = 0.f;
  int p = p0;
  #pragma unroll 1
  for (; p + 3 < p1; p += 4){
    const int s0 = col[p], s1 = col[p+1], s2 = col[p+2], s3 = col[p+3];
    const float n0 = norm_s[s0], n1 = norm_s[s1], n2 = norm_s[s2], n3 = norm_s[s3];
    float2 v0{0.f,0.f}, v1{0.f,0.f}, v2{0.f,0.f}, v3{0.f,0.f};
    if (act){
      v0 = *(const float2*)&xb[(size_t)s0*NODE_F];
      v1 = *(const float2*)&xb[(size_t)s1*NODE_F];
      v2 = *(const float2*)&xb[(size_t)s2*NODE_F];
      v3 = *(const float2*)&xb[(size_t)s3*NODE_F];
    }
    a0 = fmaf(v0.x,n0, fmaf(v1.x,n1, fmaf(v2.x,n2, fmaf(v3.x,n3, a0))));
    a1 = fmaf(v0.y,n0, fmaf(v1.y,n1, fmaf(v2.y,n2, fmaf(v3.y,n3, a1))));
  }
  const int rem = p1 - p;
  if (rem > 0){
    const int s0 = col[p];
    int s1 = s0, s2 = s0;
    float n1 = 0.f, n2 = 0.f;
    const float n0 = norm_s[s0];
    if (rem > 1){ s1 = col[p+1]; n1 = norm_s[s1]; }
    if (rem > 2){ s2 = col[p+2]; n2 = norm_s[s2]; }
    float2 v0{0.f,0.f}, v1{0.f,0.f}, v2{0.f,0.f};
    if (act){
      v0 = *(const float2*)&xb[(size_t)s0*NODE_F];
      v1 = *(const float2*)&xb[(size_t)s1*NODE_F];
      v2 = *(const float2*)&xb[(size_t)s2*NODE_F];
    }
    a0 = fmaf(v0.x,n0, fmaf(v1.x,n1, fmaf(v2.x,n2, a0)));
    a1 = fmaf(v0.y,n0, fmaf(v1.y,n1, fmaf(v2.y,n2, a1)));
  }
  if (lane < 48){
    const float nd = norm_d[row];
    ag1[(size_t)row*48 + lane] = packbf(a0*nd, a1*nd);
  }
}

// ---------------- dense GEMM layer1 (LDS-staged B, 512-thr, persistent) ------
__global__ __launch_bounds__(512) void k_ggemm1(
    const u16* __restrict__ ag1, const float* __restrict__ x0,
    const u16* __restrict__ Bp, const float* __restrict__ bg_,
    const float* __restrict__ br_, const float* __restrict__ norm_s,
    u16* __restrict__ h1, u16* __restrict__ h1s, int wh1s, int n){
  constexpr int FR1 = 8*3*512;                 // 12288 u16 per matrix
  __shared__ __align__(16) u16 sB[2*FR1];      // 48 KB
  {
    const uint4* s4 = (const uint4*)Bp;
    uint4* d4 = (uint4*)sB;
    #pragma unroll
    for (int i = 0; i < 6; ++i)
      d4[threadIdx.x + i*512] = s4[threadIdx.x + i*512];   // 2*FR1/8 = 3072
  }
  __syncthreads();
  const int lane = threadIdx.x & 63;
  const int wid  = threadIdx.x >> 6;           // 0..7
  const int jg = lane & 15, kg = lane >> 4;
  const int kb = kg*8;
  const int nb = (n + 127) >> 7;
  for (int bt = blockIdx.x; bt < nb; bt += gridDim.x){
    const int r0 = bt*128 + wid*16;
    if (r0 >= n) continue;
    const int row = r0 + jg;
    const bool rok = row < n;
    const int rA = rok ? row : (n-1);

    bf16x8 ag[3], ar[3];
    #pragma unroll
    for (int s = 0; s < 3; ++s)
      ag[s] = __builtin_bit_cast(bf16x8, *(const s16x8*)&ag1[(size_t)rA*96 + s*32 + kb]);
    {
      const float* px = x0 + (size_t)rA*NODE_F;
      #pragma unroll
      for (int s = 0; s < 2; ++s)
        #pragma unroll
        for (int e = 0; e < 8; e += 2){
          const float2 w = *(const float2*)&px[s*32 + kb + e];
          ar[s][e]   = (__bf16)w.x;
          ar[s][e+1] = (__bf16)w.y;
        }
      #pragma unroll
      for (int e = 0; e < 8; ++e) ar[2][e] = (__bf16)0.f;
      if (kg == 0){
        #pragma unroll
        for (int e = 0; e < 8; e += 2){
          const float2 w = *(const float2*)&px[64 + e];
          ar[2][e]   = (__bf16)w.x;
          ar[2][e+1] = (__bf16)w.y;
        }
      } else if (kg == 1){
        const float2 w = *(const float2*)&px[72];
        ar[2][0] = (__bf16)w.x;
        ar[2][1] = (__bf16)w.y;
      }
    }

    f32x4 accg[8], accr[8];
    #pragma unroll
    for (int t = 0; t < 8; ++t){
      accg[t] = f32x4{0.f,0.f,0.f,0.f};
      accr[t] = f32x4{0.f,0.f,0.f,0.f};
    }
    #pragma unroll
    for (int s = 0; s < 3; ++s){
      #pragma unroll
      for (int t = 0; t < 8; ++t){
        const bf16x8 bg = __builtin_bit_cast(bf16x8,
            *(const s16x8*)&sB[((t*3 + s)*64 + lane)*8]);
        const bf16x8 br = __builtin_bit_cast(bf16x8,
            *(const s16x8*)&sB[FR1 + ((t*3 + s)*64 + lane)*8]);
        accg[t] = __builtin_amdgcn_mfma_f32_16x16x32_bf16(ag[s], bg, accg[t], 0,0,0);
        accr[t] = __builtin_amdgcn_mfma_f32_16x16x32_bf16(ar[s], br, accr[t], 0,0,0);
      }
    }

    const int rowb = r0 + 4*kg;
    float ns4[4];
    #pragma unroll
    for (int r = 0; r < 4; ++r)
      ns4[r] = (wh1s && rowb + r < n) ? norm_s[rowb + r] : 0.f;
    #pragma unroll
    for (int t = 0; t < 8; ++t){
      const int colc = t*16 + jg;
      const float bgv = bg_[colc], brv = br_[colc];
      #pragma unroll
      for (int r = 0; r < 4; ++r){
        const int row2 = rowb + r;
        if (row2 < n){
          const float o = fmaxf(accg[t][r] + bgv, 0.f) + fmaxf(accr[t][r] + brv, 0.f);
          h1[(size_t)row2*HID + colc] = bfbits(o);
          if (wh1s) h1s[(size_t)row2*HID + colc] = bfbits(o * ns4[r]);
        }
      }
    }
  }
}

// ---------------- dense GEMM layer2 + fused readout (LDS, 512-thr) -----------
__global__ __launch_bounds__(512) void k_ggemm2(
    const u16* __restrict__ ag2, const u16* __restrict__ h1,
    const u16* __restrict__ Bp, const float* __restrict__ bg_,
    const float* __restrict__ br_,
    const float* __restrict__ w_atom, const float* __restrict__ b_atom,
    const int* __restrict__ gid,
    float* __restrict__ hsum, u32* __restrict__ hmax, int n){
  constexpr int FR2 = 8*4*512;                 // 16384 u16 per matrix
  __shared__ __align__(16) u16 sB[2*FR2];      // 64 KB
  {
    const uint4* s4 = (const uint4*)Bp;
    uint4* d4 = (uint4*)sB;
    #pragma unroll
    for (int i = 0; i < 8; ++i)
      d4[threadIdx.x + i*512] = s4[threadIdx.x + i*512];   // 2*FR2/8 = 4096
  }
  __syncthreads();
  const int lane = threadIdx.x & 63;
  const int wid  = threadIdx.x >> 6;           // 0..7
  const int jg = lane & 15, kg = lane >> 4;
  const int kb = kg*8;
  const int nb = (n + 127) >> 7;
  for (int bt = blockIdx.x; bt < nb; bt += gridDim.x){
    const int r0 = bt*128 + wid*16;
    if (r0 >= n) continue;
    const int row = r0 + jg;
    const bool rok = row < n;
    const int rA = rok ? row : (n-1);

    f32x4 accg[8], accr[8];
    #pragma unroll
    for (int t = 0; t < 8; ++t){
      accg[t] = f32x4{0.f,0.f,0.f,0.f};
      accr[t] = f32x4{0.f,0.f,0.f,0.f};
    }
    #pragma unroll
    for (int s = 0; s < 4; ++s){
      const bf16x8 agf = __builtin_bit_cast(bf16x8,
          *(const s16x8*)&ag2[(size_t)rA*HID + s*32 + kb]);
      const bf16x8 arf = __builtin_bit_cast(bf16x8,
          *(const s16x8*)&h1[(size_t)rA*HID + s*32 + kb]);
      #pragma unroll
      for (int t = 0; t < 8; ++t){
        const bf16x8 bg = __builtin_bit_cast(bf16x8,
            *(const s16x8*)&sB[((t*4 + s)*64 + lane)*8]);
        const bf16x8 br = __builtin_bit_cast(bf16x8,
            *(const s16x8*)&sB[FR2 + ((t*4 + s)*64 + lane)*8]);
        accg[t] = __builtin_amdgcn_mfma_f32_16x16x32_bf16(agf, bg, accg[t], 0,0,0);
        accr[t] = __builtin_amdgcn_mfma_f32_16x16x32_bf16(arf, br, accr[t], 0,0,0);
      }
    }

    float o[8][4];
    #pragma unroll
    for (int t = 0; t < 8; ++t){
      const int colc = t*16 + jg;
      const float bgv = bg_[colc], brv = br_[colc];
      #pragma unroll
      for (int r = 0; r < 4; ++r)
        o[t][r] = fmaxf(accg[t][r] + bgv, 0.f) + fmaxf(accr[t][r] + brv, 0.f);
    }
    float wa[8];
    #pragma unroll
    for (int t = 0; t < 8; ++t) wa[t] = w_atom[t*16 + jg];
    const float ba = b_atom[0];
    const int rowb = r0 + 4*kg;
    float awv[4]; int gidr[4];
    #pragma unroll
    for (int r = 0; r < 4; ++r){
      const int row2 = rowb + r;
      float dot = 0.f;
      #pragma unroll
      for (int t = 0; t < 8; ++t) dot = fmaf(o[t][r], wa[t], dot);
      dot += __shfl_xor(dot, 1);
      dot += __shfl_xor(dot, 2);
      dot += __shfl_xor(dot, 4);
      dot += __shfl_xor(dot, 8);
      awv[r]  = 1.0f/(1.0f + __expf(-(dot + ba)));
      gidr[r] = (row2 < n) ? gid[row2] : -1;
    }
    const int rhi    = (r0 + 15 < n) ? (r0 + 15) : (n - 1);
    const int gfirst = gid[r0];
    const int glast  = gid[rhi];
    for (int g = gfirst; g <= glast; ++g){
      #pragma unroll
      for (int t = 0; t < 8; ++t){
        float sv = 0.f, mv = 0.f;
        #pragma unroll
        for (int r = 0; r < 4; ++r){
          const bool in = (gidr[r] == g);
          sv += in ? o[t][r]*awv[r] : 0.f;
          mv  = in ? fmaxf(mv, o[t][r]) : mv;
        }
        sv += __shfl_xor(sv, 16);
        sv += __shfl_xor(sv, 32);
        mv  = fmaxf(mv, __shfl_xor(mv, 16));
        mv  = fmaxf(mv, __shfl_xor(mv, 32));
        if (lane < 16){
          atomicAdd(&hsum[(size_t)g*HID + t*16 + jg], sv);
          atomicMax(&hmax[(size_t)g*HID + t*16 + jg], __float_as_uint(mv));  // o >= 0
        }
      }
    }
  }
}

// ---------------- fused MLP: latent = relu(gfeat@Wp1+bp1)@Wp2+bp2, zero-row insert
__global__ __launch_bounds__(256) void k_mlp(
    const float* __restrict__ hsum, const float* __restrict__ hmaxf,
    const float* __restrict__ Wp1, const float* __restrict__ bp1,
    const float* __restrict__ Wp2, const float* __restrict__ bp2,
    const int* __restrict__ idxw, int K_,
    float* __restrict__ out, int G_){
  const int lane = threadIdx.x & 63;
  const int row = blockIdx.x*4 + (threadIdx.x >> 6);
  if (blockIdx.x == 0){
    for (int j = 0; j < K_; ++j){
      const int zr = idxw[j];
      for (int i = threadIdx.x; i < DIM; i += 256)
        out[(size_t)zr*DIM + i] = 0.f;
    }
  }
  if (row >= G_) return;
  const int c = lane*2;
  float ra0 = hsum [(size_t)row*HID + lane];
  float ra1 = hsum [(size_t)row*HID + 64 + lane];
  float ra2 = hmaxf[(size_t)row*HID + lane];
  float ra3 = hmaxf[(size_t)row*HID + 64 + lane];
  float a0 = 0.f, a1 = 0.f;
  #pragma unroll 4
  for (int k = 0; k < 64; ++k){
    const float v0 = rdl(ra0,k), v1 = rdl(ra1,k), v2 = rdl(ra2,k), v3 = rdl(ra3,k);
    const float2 w0 = *(const float2*)&Wp1[(size_t)(k      )*HID + c];
    const float2 w1 = *(const float2*)&Wp1[(size_t)(k +  64)*HID + c];
    const float2 w2 = *(const float2*)&Wp1[(size_t)(k + 128)*HID + c];
    const float2 w3 = *(const float2*)&Wp1[(size_t)(k + 192)*HID + c];
    a0 = fmaf(v0,w0.x, fmaf(v1,w1.x, fmaf(v2,w2.x, fmaf(v3,w3.x, a0))));
    a1 = fmaf(v0,w0.y, fmaf(v1,w1.y, fmaf(v2,w2.y, fmaf(v3,w3.y, a1))));
  }
  const float h0  = fmaxf(a0 + bp1[c],   0.f);
  const float h1v = fmaxf(a1 + bp1[c+1], 0.f);
  const int c4 = lane*4;
  float acc0=0.f, acc1=0.f, acc2=0.f, acc3=0.f;
  #pragma unroll 4
  for (int j = 0; j < 64; ++j){
    const float he = rdl(h0, j);
    const float ho = rdl(h1v, j);
    const float4 we = *(const float4*)&Wp2[(size_t)(2*j  )*DIM + c4];
    const float4 wo = *(const float4*)&Wp2[(size_t)(2*j+1)*DIM + c4];
    acc0 = fmaf(he,we.x, fmaf(ho,wo.x, acc0));
    acc1 = fmaf(he,we.y, fmaf(ho,wo.y, acc1));
    acc2 = fmaf(he,we.z, fmaf(ho,wo.z, acc2));
    acc3 = fmaf(he,we.w, fmaf(ho,wo.w, acc3));
  }
  int orow = row;
  for (int j = 0; j < K_; ++j){ if (idxw[j] <= orow) orow++; }
  float* po = out + (size_t)orow*DIM + c4;
  po[0] = acc0 + bp2[c4];
  po[1] = acc1 + bp2[c4+1];
  po[2] = acc2 + bp2[c4+2];
  po[3] = acc3 + bp2[c4+3];
}

extern "C" void kernel_launch(void* const* d_in, const int* in_sizes, int n_in,
                              void* d_out, int out_size, void* d_ws, size_t ws_size,
                              hipStream_t stream){
  (void)n_in;
  const float* x0     = (const float*)d_in[0];
  const float* W1     = (const float*)d_in[2];
  const float* b1     = (const float*)d_in[3];
  const float* Wr1    = (const float*)d_in[4];
  const float* br1    = (const float*)d_in[5];
  const float* W2     = (const float*)d_in[6];
  const float* b2     = (const float*)d_in[7];
  const float* Wr2    = (const float*)d_in[8];
  const float* br2    = (const float*)d_in[9];
  const float* w_atom = (const float*)d_in[10];
  const float* b_atom = (const float*)d_in[11];
  const float* Wp1    = (const float*)d_in[12];
  const float* bp1    = (const float*)d_in[13];
  const float* Wp2    = (const float*)d_in[14];
  const float* bp2    = (const float*)d_in[15];
  const int* src  = (const int*)d_in[16];
  const int* dst  = (const int*)d_in[17];
  const int* gid  = (const int*)d_in[18];
  const int* idxw = (const int*)d_in[19];

  const int N_ = in_sizes[0] / NODE_F;
  const int E_ = in_sizes[16];
  const int K_ = in_sizes[19];
  const int G_ = out_size / DIM - K_;

  // workspace (proven layout rounds 8-10, + optional h1s tail):
  u16*   h1     = (u16*)d_ws;
  float* norm_d = (float*)(h1 + (size_t)N_*HID);
  float* norm_s = norm_d + N_;
  float* hsum   = norm_s + N_;
  float* hmaxv  = hsum + (size_t)G_*HID;
  int*   indeg  = (int*)(hmaxv + (size_t)G_*HID);
  int*   row_ptr= indeg + N_;
  int*   col    = row_ptr + ((N_ + 4) & ~3);
  int*   bsum   = col + ((E_ + 4) & ~3);
  const int nscan = (N_ + 1023)/1024;
  uintptr_t aggp = ((uintptr_t)(bsum + nscan) + 255) & ~(uintptr_t)255;
  u32* aggu = (u32*)aggp;                              // [N][64] u32 (25.6 MB)
  uintptr_t x0bfp = aggp + (size_t)N_*64*sizeof(u32);
  u32* x0bf = (u32*)x0bfp;                             // [N][48] u32 (19.2 MB)
  const size_t need_bf = (x0bfp + (size_t)N_*48*sizeof(u32)) - (uintptr_t)d_ws;
  const bool use_bf = (ws_size >= need_bf);
  uintptr_t h1sp = x0bfp + (size_t)N_*48*sizeof(u32);  // 256-aligned
  u16* h1s = (u16*)h1sp;                               // [N][128] u16 (25.6 MB)
  const size_t need_h1s = (h1sp + (size_t)N_*HID*sizeof(u16)) - (uintptr_t)d_ws;
  const bool use_h1s = use_bf && (ws_size >= need_h1s);

  // weight-fragment scratch in d_out (112 KB; fully overwritten by k_mlp later)
  u16*   Bp1    = (u16*)d_out;                         // 2*12288 u16
  u16*   Bp2    = Bp1 + 2*12288;                       // 2*16384 u16

  hipMemsetAsync(norm_s, 0, ((size_t)2*N_ + (size_t)2*G_*HID)*sizeof(float), stream);

  k_deg_prep<<<(E_+255)/256, 256, 0, stream>>>(src, dst, norm_s, indeg, E_,
                                               W1, Wr1, W2, Wr2, Bp1, Bp2);
  k_scan_a  <<<nscan, 256, 0, stream>>>(indeg, norm_s, norm_d, bsum, N_);
  k_scan_b  <<<1, 1024, 0, stream>>>(bsum, nscan);
  k_scan_c  <<<nscan, 256, 0, stream>>>(indeg, bsum, row_ptr, N_);

  const int conv_tot = use_bf ? (N_*48 > E_ ? N_*48 : E_) : E_;
  k_fill_conv<<<(conv_tot+255)/256, 256, 0, stream>>>(
      src, dst, row_ptr, indeg, col, E_, x0, norm_s,
      use_bf ? x0bf : aggu, N_, use_bf ? 1 : 0);

  const int nbw  = (N_ + 3) / 4;      // fallback: 1 row/wave
  const int nbw2 = (N_ + 7) / 8;      // 2 rows/wave, 4 waves/block
  const int nb7  = (N_ + 127) / 128;  // 512-thread ggemm tiles
  const int gg   = (nb7 < 512) ? nb7 : 512;   // 2 blocks/CU
  if (use_bf){
    k_gather1b<<<nbw2, 256, 0, stream>>>(x0bf, row_ptr, col, norm_d, aggu, N_);
  } else {
    k_gather1f<<<nbw, 256, 0, stream>>>(x0, row_ptr, col, norm_s, norm_d, aggu, N_);
  }
  k_ggemm1<<<gg, 512, 0, stream>>>((const u16*)aggu, x0, Bp1, b1, br1, norm_s,
                                   h1, h1s, use_h1s ? 1 : 0, N_);
  if (use_h1s){
    k_gather2s<<<nbw2, 256, 0, stream>>>((const u32*)h1s, row_ptr, col, norm_d,
                                         aggu, N_);
  } else {
    k_gather2b<<<nbw2, 256, 0, stream>>>((const u32*)h1, row_ptr, col, norm_s,
                                         norm_d, aggu, N_);
  }
  k_ggemm2<<<gg, 512, 0, stream>>>((const u16*)aggu, h1, Bp2, b2, br2,
                                   w_atom, b_atom, gid, hsum, (u32*)hmaxv, N_);

  k_mlp<<<(G_+3)/4, 256, 0, stream>>>(hsum, hmaxv, Wp1, bp1, Wp2, bp2,
                                      idxw, K_, (float*)d_out, G_);
}

// Round 12
// 332.952 us; speedup vs baseline: 1.1676x; 1.0064x over previous
//
#include <hip/hip_runtime.h>
#include <hip/hip_bf16.h>
#include <stdint.h>

#define NODE_F 74
#define HID 128
#define DIM 256

typedef __hip_bfloat16 bf16;
typedef unsigned int u32;
typedef unsigned short u16;

typedef short s16x8 __attribute__((ext_vector_type(8)));
typedef __bf16 bf16x8 __attribute__((ext_vector_type(8)));
typedef float f32x4 __attribute__((ext_vector_type(4)));

__device__ __forceinline__ float rdl(float v, int l){
  return __int_as_float(__builtin_amdgcn_readlane(__float_as_int(v), l));
}
__device__ __forceinline__ float2 bfpair(u32 u){
  float2 r;
  r.x = __uint_as_float(u << 16);
  r.y = __uint_as_float(u & 0xffff0000u);
  return r;
}
__device__ __forceinline__ u32 packbf(float a, float b){
  u32 lo = (u32)__bfloat16_as_ushort(__float2bfloat16(a));
  u32 hi = (u32)__bfloat16_as_ushort(__float2bfloat16(b));
  return lo | (hi << 16);
}
__device__ __forceinline__ u16 bfbits(float a){
  return __bfloat16_as_ushort(__float2bfloat16(a));
}

// ---------------- degrees + weight prepack (merged) ----------------
__global__ void k_deg_prep(const int* __restrict__ src, const int* __restrict__ dst_,
                           float* __restrict__ outdeg_f, int* __restrict__ indeg, int E_,
                           const float* __restrict__ W1, const float* __restrict__ Wr1,
                           const float* __restrict__ W2, const float* __restrict__ Wr2,
                           u16* __restrict__ Bp1, u16* __restrict__ Bp2){
  int e = blockIdx.x*256 + threadIdx.x;
  if (e < E_){
    atomicAdd(&outdeg_f[src[e]], 1.0f);
    atomicAdd(&indeg[dst_[e]], 1);
  }
  int idx = e;
  if (idx < 57344){
    const float* W; u16* dstp; int S, Ktrue, loc;
    if      (idx < 12288){ W = W1;  dstp = Bp1;          S = 3; Ktrue = NODE_F; loc = idx; }
    else if (idx < 24576){ W = Wr1; dstp = Bp1 + 12288;  S = 3; Ktrue = NODE_F; loc = idx - 12288; }
    else if (idx < 40960){ W = W2;  dstp = Bp2;          S = 4; Ktrue = HID;    loc = idx - 24576; }
    else                 { W = Wr2; dstp = Bp2 + 16384;  S = 4; Ktrue = HID;    loc = idx - 40960; }
    const int el  = loc & 7;
    const int l   = (loc >> 3) & 63;
    const int rem = loc >> 9;
    const int s   = rem % S;
    const int t   = rem / S;
    const int k   = s*32 + (l >> 4)*8 + el;
    const int c   = t*16 + (l & 15);
    const float v = (k < Ktrue) ? W[(size_t)k*HID + c] : 0.f;
    dstp[loc] = bfbits(v);
  }
}

// ---------------- CSR build: 2-phase scan (block sums; offsets in phase c) ----
__global__ __launch_bounds__(256) void k_scan_a(const int* __restrict__ indeg,
                                                float* __restrict__ norm_s,
                                                float* __restrict__ norm_d,
                                                int* __restrict__ bsum, int n){
  __shared__ int red[256];
  const int base = blockIdx.x*1024 + threadIdx.x*4;
  int s = 0;
  #pragma unroll
  for (int i = 0; i < 4; ++i){
    const int idx = base + i;
    if (idx < n){
      const int d = indeg[idx];
      s += d;
      norm_d[idx] = rsqrtf(fmaxf((float)d, 1.0f));
      norm_s[idx] = rsqrtf(fmaxf(norm_s[idx], 1.0f));
    }
  }
  red[threadIdx.x] = s;
  __syncthreads();
  #pragma unroll
  for (int off = 128; off; off >>= 1){
    if (threadIdx.x < off) red[threadIdx.x] += red[threadIdx.x + off];
    __syncthreads();
  }
  if (threadIdx.x == 0) bsum[blockIdx.x] = red[0];
}

// phase c: each block derives its exclusive offset from raw bsum (nscan small),
// then intra-block scan -> row_ptr; zero indeg (becomes cursor)
__global__ __launch_bounds__(256) void k_scan_c(int* __restrict__ indeg,
                                                const int* __restrict__ bsum,
                                                int* __restrict__ row_ptr,
                                                int n, int nscan){
  __shared__ int part[256];
  // exclusive block offset = sum of bsum[0..blockIdx.x-1]
  int offs = 0;
  for (int c0 = 0; c0 < nscan; c0 += 256){
    const int t = c0 + (int)threadIdx.x;
    part[threadIdx.x] = (t < nscan && t < (int)blockIdx.x) ? bsum[t] : 0;
    __syncthreads();
    #pragma unroll
    for (int off = 128; off; off >>= 1){
      if (threadIdx.x < off) part[threadIdx.x] += part[threadIdx.x + off];
      __syncthreads();
    }
    offs += part[0];
    __syncthreads();
  }
  const int base = blockIdx.x*1024 + threadIdx.x*4;
  int v[4]; int s = 0;
  #pragma unroll
  for (int i = 0; i < 4; ++i){
    const int idx = base + i;
    v[i] = (idx < n) ? indeg[idx] : 0;
    s += v[i];
  }
  part[threadIdx.x] = s;
  __syncthreads();
  for (int off = 1; off < 256; off <<= 1){
    const int t = (threadIdx.x >= off) ? part[threadIdx.x-off] : 0;
    __syncthreads();
    part[threadIdx.x] += t;
    __syncthreads();
  }
  int run = offs + ((threadIdx.x == 0) ? 0 : part[threadIdx.x-1]);
  #pragma unroll
  for (int i = 0; i < 4; ++i){
    const int idx = base + i;
    if (idx < n){
      row_ptr[idx] = run;
      run += v[i];
      indeg[idx] = 0;
    }
    if (idx == n-1) row_ptr[n] = run;
  }
}

// ---------------- CSR fill + pre-scaled bf16 x0 conversion ----------
__global__ void k_fill_conv(const int* __restrict__ src, const int* __restrict__ dst,
                            const int* __restrict__ row_ptr, int* __restrict__ cursor,
                            int* __restrict__ col, int E_,
                            const float* __restrict__ x0,
                            const float* __restrict__ norm_s,
                            u32* __restrict__ x0bf, int n, int do_conv){
  int e = blockIdx.x*256 + threadIdx.x;
  if (e < E_){
    int d = dst[e];
    int pos = row_ptr[d] + atomicAdd(&cursor[d], 1);
    col[pos] = src[e];
  }
  if (do_conv){
    const int tot = n*48;
    if (e < tot){
      const int r = e/48, l = e - r*48;
      const int f0 = 2*l, f1 = 2*l + 1;
      const float ns = norm_s[r];
      const float u0 = (f0 < NODE_F) ? ns*x0[(size_t)r*NODE_F + f0] : 0.f;
      const float u1 = (f1 < NODE_F) ? ns*x0[(size_t)r*NODE_F + f1] : 0.f;
      x0bf[e] = packbf(u0, u1);
    }
  }
}

// ---------------- gather1b: 2 rows/wave, chunk-8, pre-scaled bf16 x0 [N][48] --
__global__ __launch_bounds__(256, 8) void k_gather1b(
    const u32* __restrict__ x0bf, const int* __restrict__ row_ptr,
    const int* __restrict__ col, const float* __restrict__ norm_d,
    u32* __restrict__ ag1, int n){
  const int lane = threadIdx.x & 63;
  const int wv   = (blockIdx.x*256 + threadIdx.x) >> 6;
  const int r0   = wv*2;
  if (r0 >= n) return;
  int p[2], e[2];
  p[0] = row_ptr[r0]; e[0] = row_ptr[r0+1];
  const bool ok1 = (r0+1) < n;
  p[1] = ok1 ? e[0] : 0;
  e[1] = ok1 ? row_ptr[r0+2] : 0;
  const bool act = (lane < 48);
  const u32* xb = x0bf + lane;
  float a0[2] = {0.f,0.f}, a1[2] = {0.f,0.f};
  while ((p[0] < e[0]) | (p[1] < e[1])){
    int c[2];
    u32 v[2][8];
    #pragma unroll
    for (int i = 0; i < 2; ++i){
      int d = e[i] - p[i];
      c[i] = (d > 8) ? 8 : ((d < 0) ? 0 : d);
      #pragma unroll
      for (int j = 0; j < 8; ++j) v[i][j] = 0u;
      if (c[i] > 0 && act){
        #pragma unroll
        for (int j = 0; j < 8; ++j){
          const int sj = col[p[i] + ((j < c[i]) ? j : (c[i]-1))];
          const u32 t = xb[(size_t)sj*48];
          v[i][j] = (j < c[i]) ? t : 0u;
        }
      }
    }
    #pragma unroll
    for (int i = 0; i < 2; ++i){
      float s0 = 0.f, s1 = 0.f;
      #pragma unroll
      for (int j = 0; j < 8; ++j){
        const float2 f = bfpair(v[i][j]);
        s0 += f.x; s1 += f.y;
      }
      a0[i] += s0; a1[i] += s1;
      p[i] += c[i];
    }
  }
  if (lane < 48){
    #pragma unroll
    for (int i = 0; i < 2; ++i){
      const int row = r0 + i;
      if (row < n){
        const float nd = norm_d[row];
        ag1[(size_t)row*48 + lane] = packbf(a0[i]*nd, a1[i]*nd);
      }
    }
  }
}

// ---------------- gather2s: 2 rows/wave, chunk-8, pre-scaled bf16 h1s [N][128]
__global__ __launch_bounds__(256, 8) void k_gather2s(
    const u32* __restrict__ h1su, const int* __restrict__ row_ptr,
    const int* __restrict__ col, const float* __restrict__ norm_d,
    u32* __restrict__ ag2, int n){
  const int lane = threadIdx.x & 63;
  const int wv   = (blockIdx.x*256 + threadIdx.x) >> 6;
  const int r0   = wv*2;
  if (r0 >= n) return;
  int p[2], e[2];
  p[0] = row_ptr[r0]; e[0] = row_ptr[r0+1];
  const bool ok1 = (r0+1) < n;
  p[1] = ok1 ? e[0] : 0;
  e[1] = ok1 ? row_ptr[r0+2] : 0;
  const u32* hb = h1su + lane;
  float a0[2] = {0.f,0.f}, a1[2] = {0.f,0.f};
  while ((p[0] < e[0]) | (p[1] < e[1])){
    int c[2];
    u32 v[2][8];
    #pragma unroll
    for (int i = 0; i < 2; ++i){
      int d = e[i] - p[i];
      c[i] = (d > 8) ? 8 : ((d < 0) ? 0 : d);
      #pragma unroll
      for (int j = 0; j < 8; ++j) v[i][j] = 0u;
      if (c[i] > 0){
        #pragma unroll
        for (int j = 0; j < 8; ++j){
          const int sj = col[p[i] + ((j < c[i]) ? j : (c[i]-1))];
          const u32 t = hb[(size_t)sj*64];
          v[i][j] = (j < c[i]) ? t : 0u;
        }
      }
    }
    #pragma unroll
    for (int i = 0; i < 2; ++i){
      float s0 = 0.f, s1 = 0.f;
      #pragma unroll
      for (int j = 0; j < 8; ++j){
        const float2 f = bfpair(v[i][j]);
        s0 += f.x; s1 += f.y;
      }
      a0[i] += s0; a1[i] += s1;
      p[i] += c[i];
    }
  }
  #pragma unroll
  for (int i = 0; i < 2; ++i){
    const int row = r0 + i;
    if (row < n){
      const float nd = norm_d[row];
      ag2[(size_t)row*64 + lane] = packbf(a0[i]*nd, a1[i]*nd);
    }
  }
}

// ---------------- gather2b: fallback, 2 rows/wave chunk-4, unscaled h1 -------
__global__ __launch_bounds__(256, 8) void k_gather2b(
    const u32* __restrict__ h1u, const int* __restrict__ row_ptr,
    const int* __restrict__ col, const float* __restrict__ norm_s,
    const float* __restrict__ norm_d, u32* __restrict__ ag2, int n){
  const int lane = threadIdx.x & 63;
  const int wv   = (blockIdx.x*256 + threadIdx.x) >> 6;
  const int r0   = wv*2;
  if (r0 >= n) return;
  int p[2], e[2];
  p[0] = row_ptr[r0]; e[0] = row_ptr[r0+1];
  const bool ok1 = (r0+1) < n;
  p[1] = ok1 ? e[0] : 0;
  e[1] = ok1 ? row_ptr[r0+2] : 0;
  const u32* hb = h1u + lane;
  float a0[2] = {0.f,0.f}, a1[2] = {0.f,0.f};
  while ((p[0] < e[0]) | (p[1] < e[1])){
    int c[2], s[2][4];
    #pragma unroll
    for (int i = 0; i < 2; ++i){
      int d = e[i] - p[i];
      c[i] = (d > 4) ? 4 : ((d < 0) ? 0 : d);
      if (c[i] > 0){
        #pragma unroll
        for (int j = 0; j < 4; ++j)
          s[i][j] = col[p[i] + ((j < c[i]) ? j : (c[i]-1))];
      }
    }
    float nw[2][4];
    u32 v[2][4];
    #pragma unroll
    for (int i = 0; i < 2; ++i){
      #pragma unroll
      for (int j = 0; j < 4; ++j){ nw[i][j] = 0.f; v[i][j] = 0u; }
      if (c[i] > 0){
        #pragma unroll
        for (int j = 0; j < 4; ++j) nw[i][j] = (j < c[i]) ? norm_s[s[i][j]] : 0.f;
        #pragma unroll
        for (int j = 0; j < 4; ++j) v[i][j] = hb[(size_t)s[i][j]*64];
      }
    }
    #pragma unroll
    for (int i = 0; i < 2; ++i){
      const float2 f0 = bfpair(v[i][0]), f1 = bfpair(v[i][1]);
      const float2 f2 = bfpair(v[i][2]), f3 = bfpair(v[i][3]);
      a0[i] = fmaf(f0.x, nw[i][0], fmaf(f1.x, nw[i][1],
              fmaf(f2.x, nw[i][2], fmaf(f3.x, nw[i][3], a0[i]))));
      a1[i] = fmaf(f0.y, nw[i][0], fmaf(f1.y, nw[i][1],
              fmaf(f2.y, nw[i][2], fmaf(f3.y, nw[i][3], a1[i]))));
      p[i] += c[i];
    }
  }
  #pragma unroll
  for (int i = 0; i < 2; ++i){
    const int row = r0 + i;
    if (row < n){
      const float nd = norm_d[row];
      ag2[(size_t)row*64 + lane] = packbf(a0[i]*nd, a1[i]*nd);
    }
  }
}

// ---------------- fallback gather1 (round-7 proven, f32 x0) ------------------
__global__ __launch_bounds__(256) void k_gather1f(
    const float* __restrict__ x0, const int* __restrict__ row_ptr,
    const int* __restrict__ col, const float* __restrict__ norm_s,
    const float* __restrict__ norm_d, u32* __restrict__ ag1, int n){
  const int lane = threadIdx.x & 63;
  const int row  = blockIdx.x*4 + (threadIdx.x >> 6);
  if (row >= n) return;
  const int p0 = row_ptr[row], p1 = row_ptr[row+1];
  const bool act = (lane < 37);
  const float* xb = x0 + 2*lane;
  float a0 = 0.f, a1 = 0.f;
  int p = p0;
  #pragma unroll 1
  for (; p + 3 < p1; p += 4){
    const int s0 = col[p], s1 = col[p+1], s2 = col[p+2], s3 = col[p+3];
    const float n0 = norm_s[s0], n1 = norm_s[s1], n2 = norm_s[s2], n3 = norm_s[s3];
    float2 v0{0.f,0.f}, v1{0.f,0.f}, v2{0.f,0.f}, v3{0.f,0.f};
    if (act){
      v0 = *(const float2*)&xb[(size_t)s0*NODE_F];
      v1 = *(const float2*)&xb[(size_t)s1*NODE_F];
      v2 = *(const float2*)&xb[(size_t)s2*NODE_F];
      v3 = *(const float2*)&xb[(size_t)s3*NODE_F];
    }
    a0 = fmaf(v0.x,n0, fmaf(v1.x,n1, fmaf(v2.x,n2, fmaf(v3.x,n3, a0))));
    a1 = fmaf(v0.y,n0, fmaf(v1.y,n1, fmaf(v2.y,n2, fmaf(v3.y,n3, a1))));
  }
  const int rem = p1 - p;
  if (rem > 0){
    const int s0 = col[p];
    int s1 = s0, s2 = s0;
    float n1 = 0.f, n2 = 0.f;
    const float n0 = norm_s[s0];
    if (rem > 1){ s1 = col[p+1]; n1 = norm_s[s1]; }
    if (rem > 2){ s2 = col[p+2]; n2 = norm_s[s2]; }
    float2 v0{0.f,0.f}, v1{0.f,0.f}, v2{0.f,0.f};
    if (act){
      v0 = *(const float2*)&xb[(size_t)s0*NODE_F];
      v1 = *(const float2*)&xb[(size_t)s1*NODE_F];
      v2 = *(const float2*)&xb[(size_t)s2*NODE_F];
    }
    a0 = fmaf(v0.x,n0, fmaf(v1.x,n1, fmaf(v2.x,n2, a0)));
    a1 = fmaf(v0.y,n0, fmaf(v1.y,n1, fmaf(v2.y,n2, a1)));
  }
  if (lane < 48){
    const float nd = norm_d[row];
    ag1[(size_t)row*48 + lane] = packbf(a0*nd, a1*nd);
  }
}

// ---------------- dense GEMM layer1 (LDS-staged B, 512-thr, persistent) ------
__global__ __launch_bounds__(512) void k_ggemm1(
    const u16* __restrict__ ag1, const float* __restrict__ x0,
    const u16* __restrict__ Bp, const float* __restrict__ bg_,
    const float* __restrict__ br_, const float* __restrict__ norm_s,
    u16* __restrict__ h1, u16* __restrict__ h1s, int wh1s, int n){
  constexpr int FR1 = 8*3*512;                 // 12288 u16 per matrix
  __shared__ __align__(16) u16 sB[2*FR1];      // 48 KB
  {
    const uint4* s4 = (const uint4*)Bp;
    uint4* d4 = (uint4*)sB;
    #pragma unroll
    for (int i = 0; i < 6; ++i)
      d4[threadIdx.x + i*512] = s4[threadIdx.x + i*512];   // 2*FR1/8 = 3072
  }
  __syncthreads();
  const int lane = threadIdx.x & 63;
  const int wid  = threadIdx.x >> 6;           // 0..7
  const int jg = lane & 15, kg = lane >> 4;
  const int kb = kg*8;
  const int nb = (n + 127) >> 7;
  for (int bt = blockIdx.x; bt < nb; bt += gridDim.x){
    const int r0 = bt*128 + wid*16;
    if (r0 >= n) continue;
    const int row = r0 + jg;
    const bool rok = row < n;
    const int rA = rok ? row : (n-1);

    bf16x8 ag[3], ar[3];
    #pragma unroll
    for (int s = 0; s < 3; ++s)
      ag[s] = __builtin_bit_cast(bf16x8, *(const s16x8*)&ag1[(size_t)rA*96 + s*32 + kb]);
    {
      const float* px = x0 + (size_t)rA*NODE_F;
      #pragma unroll
      for (int s = 0; s < 2; ++s)
        #pragma unroll
        for (int e = 0; e < 8; e += 2){
          const float2 w = *(const float2*)&px[s*32 + kb + e];
          ar[s][e]   = (__bf16)w.x;
          ar[s][e+1] = (__bf16)w.y;
        }
      #pragma unroll
      for (int e = 0; e < 8; ++e) ar[2][e] = (__bf16)0.f;
      if (kg == 0){
        #pragma unroll
        for (int e = 0; e < 8; e += 2){
          const float2 w = *(const float2*)&px[64 + e];
          ar[2][e]   = (__bf16)w.x;
          ar[2][e+1] = (__bf16)w.y;
        }
      } else if (kg == 1){
        const float2 w = *(const float2*)&px[72];
        ar[2][0] = (__bf16)w.x;
        ar[2][1] = (__bf16)w.y;
      }
    }

    f32x4 accg[8], accr[8];
    #pragma unroll
    for (int t = 0; t < 8; ++t){
      accg[t] = f32x4{0.f,0.f,0.f,0.f};
      accr[t] = f32x4{0.f,0.f,0.f,0.f};
    }
    #pragma unroll
    for (int s = 0; s < 3; ++s){
      #pragma unroll
      for (int t = 0; t < 8; ++t){
        const bf16x8 bg = __builtin_bit_cast(bf16x8,
            *(const s16x8*)&sB[((t*3 + s)*64 + lane)*8]);
        const bf16x8 br = __builtin_bit_cast(bf16x8,
            *(const s16x8*)&sB[FR1 + ((t*3 + s)*64 + lane)*8]);
        accg[t] = __builtin_amdgcn_mfma_f32_16x16x32_bf16(ag[s], bg, accg[t], 0,0,0);
        accr[t] = __builtin_amdgcn_mfma_f32_16x16x32_bf16(ar[s], br, accr[t], 0,0,0);
      }
    }

    const int rowb = r0 + 4*kg;
    float ns4[4];
    #pragma unroll
    for (int r = 0; r < 4; ++r)
      ns4[r] = (wh1s && rowb + r < n) ? norm_s[rowb + r] : 0.f;
    #pragma unroll
    for (int t = 0; t < 8; ++t){
      const int colc = t*16 + jg;
      const float bgv = bg_[colc], brv = br_[colc];
      #pragma unroll
      for (int r = 0; r < 4; ++r){
        const int row2 = rowb + r;
        if (row2 < n){
          const float o = fmaxf(accg[t][r] + bgv, 0.f) + fmaxf(accr[t][r] + brv, 0.f);
          h1[(size_t)row2*HID + colc] = bfbits(o);
          if (wh1s) h1s[(size_t)row2*HID + colc] = bfbits(o * ns4[r]);
        }
      }
    }
  }
}

// ---------------- dense GEMM layer2 + fused readout (LDS, 512-thr) -----------
__global__ __launch_bounds__(512) void k_ggemm2(
    const u16* __restrict__ ag2, const u16* __restrict__ h1,
    const u16* __restrict__ Bp, const float* __restrict__ bg_,
    const float* __restrict__ br_,
    const float* __restrict__ w_atom, const float* __restrict__ b_atom,
    const int* __restrict__ gid,
    float* __restrict__ hsum, u32* __restrict__ hmax, int n){
  constexpr int FR2 = 8*4*512;                 // 16384 u16 per matrix
  __shared__ __align__(16) u16 sB[2*FR2];      // 64 KB
  {
    const uint4* s4 = (const uint4*)Bp;
    uint4* d4 = (uint4*)sB;
    #pragma unroll
    for (int i = 0; i < 8; ++i)
      d4[threadIdx.x + i*512] = s4[threadIdx.x + i*512];   // 2*FR2/8 = 4096
  }
  __syncthreads();
  const int lane = threadIdx.x & 63;
  const int wid  = threadIdx.x >> 6;           // 0..7
  const int jg = lane & 15, kg = lane >> 4;
  const int kb = kg*8;
  const int nb = (n + 127) >> 7;
  for (int bt = blockIdx.x; bt < nb; bt += gridDim.x){
    const int r0 = bt*128 + wid*16;
    if (r0 >= n) continue;
    const int row = r0 + jg;
    const bool rok = row < n;
    const int rA = rok ? row : (n-1);

    f32x4 accg[8], accr[8];
    #pragma unroll
    for (int t = 0; t < 8; ++t){
      accg[t] = f32x4{0.f,0.f,0.f,0.f};
      accr[t] = f32x4{0.f,0.f,0.f,0.f};
    }
    #pragma unroll
    for (int s = 0; s < 4; ++s){
      const bf16x8 agf = __builtin_bit_cast(bf16x8,
          *(const s16x8*)&ag2[(size_t)rA*HID + s*32 + kb]);
      const bf16x8 arf = __builtin_bit_cast(bf16x8,
          *(const s16x8*)&h1[(size_t)rA*HID + s*32 + kb]);
      #pragma unroll
      for (int t = 0; t < 8; ++t){
        const bf16x8 bg = __builtin_bit_cast(bf16x8,
            *(const s16x8*)&sB[((t*4 + s)*64 + lane)*8]);
        const bf16x8 br = __builtin_bit_cast(bf16x8,
            *(const s16x8*)&sB[FR2 + ((t*4 + s)*64 + lane)*8]);
        accg[t] = __builtin_amdgcn_mfma_f32_16x16x32_bf16(agf, bg, accg[t], 0,0,0);
        accr[t] = __builtin_amdgcn_mfma_f32_16x16x32_bf16(arf, br, accr[t], 0,0,0);
      }
    }

    float o[8][4];
    #pragma unroll
    for (int t = 0; t < 8; ++t){
      const int colc = t*16 + jg;
      const float bgv = bg_[colc], brv = br_[colc];
      #pragma unroll
      for (int r = 0; r < 4; ++r)
        o[t][r] = fmaxf(accg[t][r] + bgv, 0.f) + fmaxf(accr[t][r] + brv, 0.f);
    }
    float wa[8];
    #pragma unroll
    for (int t = 0; t < 8; ++t) wa[t] = w_atom[t*16 + jg];
    const float ba = b_atom[0];
    const int rowb = r0 + 4*kg;
    float awv[4]; int gidr[4];
    #pragma unroll
    for (int r = 0; r < 4; ++r){
      const int row2 = rowb + r;
      float dot = 0.f;
      #pragma unroll
      for (int t = 0; t < 8; ++t) dot = fmaf(o[t][r], wa[t], dot);
      dot += __shfl_xor(dot, 1);
      dot += __shfl_xor(dot, 2);
      dot += __shfl_xor(dot, 4);
      dot += __shfl_xor(dot, 8);
      awv[r]  = 1.0f/(1.0f + __expf(-(dot + ba)));
      gidr[r] = (row2 < n) ? gid[row2] : -1;
    }
    const int rhi    = (r0 + 15 < n) ? (r0 + 15) : (n - 1);
    const int gfirst = gid[r0];
    const int glast  = gid[rhi];
    for (int g = gfirst; g <= glast; ++g){
      #pragma unroll
      for (int t = 0; t < 8; ++t){
        float sv = 0.f, mv = 0.f;
        #pragma unroll
        for (int r = 0; r < 4; ++r){
          const bool in = (gidr[r] == g);
          sv += in ? o[t][r]*awv[r] : 0.f;
          mv  = in ? fmaxf(mv, o[t][r]) : mv;
        }
        sv += __shfl_xor(sv, 16);
        sv += __shfl_xor(sv, 32);
        mv  = fmaxf(mv, __shfl_xor(mv, 16));
        mv  = fmaxf(mv, __shfl_xor(mv, 32));
        if (lane < 16){
          atomicAdd(&hsum[(size_t)g*HID + t*16 + jg], sv);
          atomicMax(&hmax[(size_t)g*HID + t*16 + jg], __float_as_uint(mv));  // o >= 0
        }
      }
    }
  }
}

// ---------------- fused MLP: latent = relu(gfeat@Wp1+bp1)@Wp2+bp2, zero-row insert
__global__ __launch_bounds__(256) void k_mlp(
    const float* __restrict__ hsum, const float* __restrict__ hmaxf,
    const float* __restrict__ Wp1, const float* __restrict__ bp1,
    const float* __restrict__ Wp2, const float* __restrict__ bp2,
    const int* __restrict__ idxw, int K_,
    float* __restrict__ out, int G_){
  const int lane = threadIdx.x & 63;
  const int row = blockIdx.x*4 + (threadIdx.x >> 6);
  if (blockIdx.x == 0){
    for (int j = 0; j < K_; ++j){
      const int zr = idxw[j];
      for (int i = threadIdx.x; i < DIM; i += 256)
        out[(size_t)zr*DIM + i] = 0.f;
    }
  }
  if (row >= G_) return;
  const int c = lane*2;
  float ra0 = hsum [(size_t)row*HID + lane];
  float ra1 = hsum [(size_t)row*HID + 64 + lane];
  float ra2 = hmaxf[(size_t)row*HID + lane];
  float ra3 = hmaxf[(size_t)row*HID + 64 + lane];
  float a0 = 0.f, a1 = 0.f;
  #pragma unroll 4
  for (int k = 0; k < 64; ++k){
    const float v0 = rdl(ra0,k), v1 = rdl(ra1,k), v2 = rdl(ra2,k), v3 = rdl(ra3,k);
    const float2 w0 = *(const float2*)&Wp1[(size_t)(k      )*HID + c];
    const float2 w1 = *(const float2*)&Wp1[(size_t)(k +  64)*HID + c];
    const float2 w2 = *(const float2*)&Wp1[(size_t)(k + 128)*HID + c];
    const float2 w3 = *(const float2*)&Wp1[(size_t)(k + 192)*HID + c];
    a0 = fmaf(v0,w0.x, fmaf(v1,w1.x, fmaf(v2,w2.x, fmaf(v3,w3.x, a0))));
    a1 = fmaf(v0,w0.y, fmaf(v1,w1.y, fmaf(v2,w2.y, fmaf(v3,w3.y, a1))));
  }
  const float h0  = fmaxf(a0 + bp1[c],   0.f);
  const float h1v = fmaxf(a1 + bp1[c+1], 0.f);
  const int c4 = lane*4;
  float acc0=0.f, acc1=0.f, acc2=0.f, acc3=0.f;
  #pragma unroll 4
  for (int j = 0; j < 64; ++j){
    const float he = rdl(h0, j);
    const float ho = rdl(h1v, j);
    const float4 we = *(const float4*)&Wp2[(size_t)(2*j  )*DIM + c4];
    const float4 wo = *(const float4*)&Wp2[(size_t)(2*j+1)*DIM + c4];
    acc0 = fmaf(he,we.x, fmaf(ho,wo.x, acc0));
    acc1 = fmaf(he,we.y, fmaf(ho,wo.y, acc1));
    acc2 = fmaf(he,we.z, fmaf(ho,wo.z, acc2));
    acc3 = fmaf(he,we.w, fmaf(ho,wo.w, acc3));
  }
  int orow = row;
  for (int j = 0; j < K_; ++j){ if (idxw[j] <= orow) orow++; }
  float* po = out + (size_t)orow*DIM + c4;
  po[0] = acc0 + bp2[c4];
  po[1] = acc1 + bp2[c4+1];
  po[2] = acc2 + bp2[c4+2];
  po[3] = acc3 + bp2[c4+3];
}

extern "C" void kernel_launch(void* const* d_in, const int* in_sizes, int n_in,
                              void* d_out, int out_size, void* d_ws, size_t ws_size,
                              hipStream_t stream){
  (void)n_in;
  const float* x0     = (const float*)d_in[0];
  const float* W1     = (const float*)d_in[2];
  const float* b1     = (const float*)d_in[3];
  const float* Wr1    = (const float*)d_in[4];
  const float* br1    = (const float*)d_in[5];
  const float* W2     = (const float*)d_in[6];
  const float* b2     = (const float*)d_in[7];
  const float* Wr2    = (const float*)d_in[8];
  const float* br2    = (const float*)d_in[9];
  const float* w_atom = (const float*)d_in[10];
  const float* b_atom = (const float*)d_in[11];
  const float* Wp1    = (const float*)d_in[12];
  const float* bp1    = (const float*)d_in[13];
  const float* Wp2    = (const float*)d_in[14];
  const float* bp2    = (const float*)d_in[15];
  const int* src  = (const int*)d_in[16];
  const int* dst  = (const int*)d_in[17];
  const int* gid  = (const int*)d_in[18];
  const int* idxw = (const int*)d_in[19];

  const int N_ = in_sizes[0] / NODE_F;
  const int E_ = in_sizes[16];
  const int K_ = in_sizes[19];
  const int G_ = out_size / DIM - K_;

  // workspace (proven layout rounds 8-11):
  u16*   h1     = (u16*)d_ws;
  float* norm_d = (float*)(h1 + (size_t)N_*HID);
  float* norm_s = norm_d + N_;
  float* hsum   = norm_s + N_;
  float* hmaxv  = hsum + (size_t)G_*HID;
  int*   indeg  = (int*)(hmaxv + (size_t)G_*HID);
  int*   row_ptr= indeg + N_;
  int*   col    = row_ptr + ((N_ + 4) & ~3);
  int*   bsum   = col + ((E_ + 4) & ~3);
  const int nscan = (N_ + 1023)/1024;
  uintptr_t aggp = ((uintptr_t)(bsum + nscan) + 255) & ~(uintptr_t)255;
  u32* aggu = (u32*)aggp;                              // [N][64] u32 (25.6 MB)
  uintptr_t x0bfp = aggp + (size_t)N_*64*sizeof(u32);
  u32* x0bf = (u32*)x0bfp;                             // [N][48] u32 (19.2 MB)
  const size_t need_bf = (x0bfp + (size_t)N_*48*sizeof(u32)) - (uintptr_t)d_ws;
  const bool use_bf = (ws_size >= need_bf);
  uintptr_t h1sp = x0bfp + (size_t)N_*48*sizeof(u32);  // 256-aligned
  u16* h1s = (u16*)h1sp;                               // [N][128] u16 (25.6 MB)
  const size_t need_h1s = (h1sp + (size_t)N_*HID*sizeof(u16)) - (uintptr_t)d_ws;
  const bool use_h1s = use_bf && (ws_size >= need_h1s);

  // weight-fragment scratch in d_out (112 KB; fully overwritten by k_mlp later)
  u16*   Bp1    = (u16*)d_out;                         // 2*12288 u16
  u16*   Bp2    = Bp1 + 2*12288;                       // 2*16384 u16

  hipMemsetAsync(norm_s, 0, ((size_t)2*N_ + (size_t)2*G_*HID)*sizeof(float), stream);

  k_deg_prep<<<(E_+255)/256, 256, 0, stream>>>(src, dst, norm_s, indeg, E_,
                                               W1, Wr1, W2, Wr2, Bp1, Bp2);
  k_scan_a  <<<nscan, 256, 0, stream>>>(indeg, norm_s, norm_d, bsum, N_);
  k_scan_c  <<<nscan, 256, 0, stream>>>(indeg, bsum, row_ptr, N_, nscan);

  const int conv_tot = use_bf ? (N_*48 > E_ ? N_*48 : E_) : E_;
  k_fill_conv<<<(conv_tot+255)/256, 256, 0, stream>>>(
      src, dst, row_ptr, indeg, col, E_, x0, norm_s,
      use_bf ? x0bf : aggu, N_, use_bf ? 1 : 0);

  const int nbw  = (N_ + 3) / 4;      // fallback: 1 row/wave
  const int nbw2 = (N_ + 7) / 8;      // 2 rows/wave, 4 waves/block
  const int nb7  = (N_ + 127) / 128;  // 512-thread ggemm tiles
  const int gg   = (nb7 < 512) ? nb7 : 512;   // 2 blocks/CU
  if (use_bf){
    k_gather1b<<<nbw2, 256, 0, stream>>>(x0bf, row_ptr, col, norm_d, aggu, N_);
  } else {
    k_gather1f<<<nbw, 256, 0, stream>>>(x0, row_ptr, col, norm_s, norm_d, aggu, N_);
  }
  k_ggemm1<<<gg, 512, 0, stream>>>((const u16*)aggu, x0, Bp1, b1, br1, norm_s,
                                   h1, h1s, use_h1s ? 1 : 0, N_);
  if (use_h1s){
    k_gather2s<<<nbw2, 256, 0, stream>>>((const u32*)h1s, row_ptr, col, norm_d,
                                         aggu, N_);
  } else {
    k_gather2b<<<nbw2, 256, 0, stream>>>((const u32*)h1, row_ptr, col, norm_s,
                                         norm_d, aggu, N_);
  }
  k_ggemm2<<<gg, 512, 0, stream>>>((const u16*)aggu, h1, Bp2, b2, br2,
                                   w_atom, b_atom, gid, hsum, (u32*)hmaxv, N_);

  k_mlp<<<(G_+3)/4, 256, 0, stream>>>(hsum, hmaxv, Wp1, bp1, Wp2, bp2,
                                      idxw, K_, (float*)d_out, G_);
}